// Round 3
// baseline (462.681 us; speedup 1.0000x reference)
//
#include <hip/hip_runtime.h>
#include <stdint.h>

// Problem constants
#define N_TOK 32768   // B*H*W tokens
#define DIM   256
#define KCB   8192
#define HWSZ  1024

// ---- workspace layout (float offsets) ---- total 8,011,776 floats = 32.0 MB
#define WS_FLATB   0u          // bf16 flat [32768][256]  (4,194,304)
#define WS_CBB     4194304u    // bf16 cb [8192][256]     (1,048,576)
#define WS_A32     5242880u    // np-fp32 ||z||^2         32,768
#define WS_B32     5275648u    // np-fp32 ||e||^2         8,192
#define WS_IDX     5283840u    // argmin (int)            32,768
#define WS_CAND    5316608u    // [token][16] int         524,288
#define WS_ICNT    5840896u    // int histogram           8,192   <- memset from here
#define WS_CUR     5849088u    // int cursors             8,192   <- memset through here
#define WS_OFFS    5857280u    // int exclusive offsets   8,192
#define WS_PERM    5865472u    // int token permutation   32,768
#define WS_LPART   5898240u    // per-block loss partials 8,192 doubles (16,384 floats)
#define WS_DW      5914624u    // segment-sum fp32        2,097,152
#define WS_TOTAL   8011776u
#define WS_MEMSET_LEN 16384u   // ICNT + CUR only

// ---- output layout (float offsets) ----
#define O_LOSS 0u
#define O_Q    1u
#define O_IDX  8388609u
#define O_CNT  8421377u
#define O_W    8429569u
#define O_CB   10526721u

typedef __attribute__((ext_vector_type(8))) short bf16x8;
typedef __attribute__((ext_vector_type(4))) float f32x4;

__device__ __forceinline__ void g2lds16(const void* gp, void* lp){
  __builtin_amdgcn_global_load_lds(
      (const __attribute__((address_space(1))) void*)gp,
      (__attribute__((address_space(3))) void*)lp, 16, 0, 0);
}

__device__ __forceinline__ unsigned short f2b(float f){   // fp32 -> bf16 RNE
  unsigned u = __float_as_uint(f);
  return (unsigned short)((u + 0x7FFFu + ((u >> 16) & 1u)) >> 16);
}

__device__ __forceinline__ unsigned umin2(unsigned a, unsigned b){ return a < b ? a : b; }
__device__ __forceinline__ unsigned umax2(unsigned a, unsigned b){ return a > b ? a : b; }

// ============ prep: x [B,C,H,W] -> flatB bf16 [token][c] (transpose) ============
__global__ void k_flatb(const float* __restrict__ x, unsigned short* __restrict__ flatB){
  __shared__ float tile[64][65];
  const int bx = blockIdx.x;                // 2048 = b(32) x ct(4) x ht(16)
  const int b = bx >> 6, ct = (bx >> 4) & 3, ht = bx & 15;
  const int c0 = ct * 64, hw0 = ht * 64;
  const int t = threadIdx.x, rr = t >> 4, cc4 = (t & 15) * 4;
  #pragma unroll
  for (int j = 0; j < 4; j++){
    const int crow = rr + j * 16;
    float4 v = *(const float4*)(x + ((size_t)(b * 256 + c0 + crow) << 10) + hw0 + cc4);
    tile[crow][cc4] = v.x; tile[crow][cc4+1] = v.y; tile[crow][cc4+2] = v.z; tile[crow][cc4+3] = v.w;
  }
  __syncthreads();
  #pragma unroll
  for (int j = 0; j < 4; j++){
    const int hwrow = rr + j * 16;
    ushort4 o = { f2b(tile[cc4][hwrow]), f2b(tile[cc4+1][hwrow]),
                  f2b(tile[cc4+2][hwrow]), f2b(tile[cc4+3][hwrow]) };
    *(ushort4*)(flatB + ((size_t)(b * 1024 + hw0 + hwrow) << 8) + c0 + cc4) = o;
  }
}

// ============ prep: codebook fp32 -> bf16 (no transpose) ============
__global__ void k_cbb(const float* __restrict__ cb, unsigned short* __restrict__ cbB){
  const int t = blockIdx.x * 256 + threadIdx.x;    // 524,288
  float4 v = *(const float4*)(cb + (size_t)t * 4);
  ushort4 o = { f2b(v.x), f2b(v.y), f2b(v.z), f2b(v.w) };
  *(ushort4*)(cbB + (size_t)t * 4) = o;
}

// ============ prep: squared norms, numpy pairwise fp32 order ============
__device__ __forceinline__ float np_pairwise_sq(const float* __restrict__ p, int stride){
  #pragma clang fp contract(off)
  float h[2];
  #pragma unroll
  for (int half = 0; half < 2; half++){
    const float* q = p + half * 128 * stride;
    float r[8];
    #pragma unroll
    for (int j = 0; j < 8; j++){ float z = q[j * stride]; r[j] = z * z; }
    for (int i = 8; i < 128; i += 8){
      #pragma unroll
      for (int j = 0; j < 8; j++){ float z = q[(i + j) * stride]; r[j] = r[j] + z * z; }
    }
    h[half] = ((r[0] + r[1]) + (r[2] + r[3])) + ((r[4] + r[5]) + (r[6] + r[7]));
  }
  return h[0] + h[1];
}

__global__ void k_sqn(const float* __restrict__ x, const float* __restrict__ cb,
                      float* __restrict__ a32, float* __restrict__ b32){
  int t = blockIdx.x * 256 + threadIdx.x;      // 40,960
  if (t < N_TOK){
    int b = t >> 10, hw = t & 1023;
    a32[t] = np_pairwise_sq(x + (size_t)b * 262144 + hw, 1024);  // flat[n][c], same order
  } else {
    int k2 = t - N_TOK;
    b32[k2] = np_pairwise_sq(cb + (size_t)k2 * 256, 1);
  }
}

// ============ phase 1: bf16-MFMA distance GEMM + top-8 candidates/half ============
// Deep-ring schedule (T2+T3+T4+T5 composed):
//  - A panel (128 tokens x 256 dims, 64KB) resident in LDS, staged once;
//    kg 4..7 A-fragments additionally cached in registers (64 VGPR).
//  - B streamed in [128 codes][64 dims] slices through a 5-deep 16KB ring.
//  - per step S: { ds_read frags of slice S (published >=2 barriers ago);
//    issue stage(S+3); s_waitcnt vmcnt(4) (waits only for stage(S+1), issued
//    2 steps earlier -> free); ONE s_barrier; 16 MFMA }.
//    Hazards: stage(S+3) overwrites the buffer read at S-2; every wave's
//    reads at S-2 drained before its MFMA_{S-2} < barrier_{S-1}, which all
//    waves passed. Tail peeled with vmcnt 4 -> 2 -> 0 (no timing assumptions).
//  - keys: float bits of (0.125 - 2*dot), (chunk<<1|jj) in low-7 mantissa bits;
//    per-lane top-2 of its 64-col slice; final 2-stage LDS merge -> top-8/half.
__launch_bounds__(512, 2)
__global__ void k_dist(const unsigned short* __restrict__ flatB,
                       const unsigned short* __restrict__ cbB,
                       int* __restrict__ cand)
{
  __shared__ __align__(16) unsigned short A1[128 * 256];   // 64 KB resident A
  __shared__ __align__(16) unsigned short Bs[5][128 * 64]; // 5 x 16 KB ring

  const int tid = threadIdx.x;
  const int bx = blockIdx.x;             // 512 = 256 token-tiles x 2 halves
  const int tt = bx >> 1, h = bx & 1;
  const int tok0 = tt * 128;
  const int wv = tid >> 6, lane = tid & 63;
  const int wy = wv >> 2, wx = wv & 3;
  const int l4 = lane >> 4, lm = lane & 15;

  const unsigned short* fB = flatB + (size_t)tok0 * 256;
  const unsigned short* cB = cbB + (size_t)h * 4096 * 256;

  // ---- stage A (64KB, 8 g2lds16 per thread; 2 rows per wave-instr) ----
  {
    const int rowA = lane >> 5, pA = lane & 31;
    #pragma unroll
    for (int j = 0; j < 8; j++){
      const int br = wv * 16 + j * 2;
      const int gr = pA ^ ((j * 2 + rowA) & 15);
      g2lds16((const char*)fB + (size_t)(br + rowA) * 512 + (gr << 4),
              (char*)A1 + br * 512);
    }
  }

  // ---- B stage invariants: per-instr 8 rows (1KB), lane -> (row lane>>3, gran lane&7)
  const char* gB0; const char* gB1;
  unsigned dst0, dst1;
  {
    const int rw = lane >> 3, p = lane & 7;
    const int gc = p ^ rw;              // row&7 == lane>>3 for our row bases
    gB0 = (const char*)cB + (size_t)(wv * 16 + 0 + rw) * 512 + (gc << 4);
    gB1 = (const char*)cB + (size_t)(wv * 16 + 8 + rw) * 512 + (gc << 4);
    dst0 = (unsigned)((wv * 16 + 0) * 128);
    dst1 = (unsigned)((wv * 16 + 8) * 128);
  }

  // ---- prologue: stage B slices 0,1,2 into rings 0,1,2 ----
  #pragma unroll
  for (int s2 = 0; s2 < 3; s2++){
    char* dst = (char*)Bs + ((unsigned)s2 << 14);
    g2lds16(gB0 + (size_t)(s2 * 128), dst + dst0);
    g2lds16(gB1 + (size_t)(s2 * 128), dst + dst1);
  }

  // drain A(8) + B0(2): leave newest 4 (B1,B2) outstanding
  asm volatile("s_waitcnt vmcnt(4)" ::: "memory");
  asm volatile("s_barrier" ::: "memory");

  // ---- A kg 4..7 fragments -> registers (16 x b128 = 64 VGPR) ----
  bf16x8 a2[4][4];
  #pragma unroll
  for (int t2 = 0; t2 < 4; t2++)
    #pragma unroll
    for (int ii = 0; ii < 4; ii++){
      const int m = wy * 64 + ii * 16 + lm;
      const int ca = 16 + t2 * 4 + l4;
      a2[t2][ii] = *(const bf16x8*)((const char*)A1 + m * 512 + ((ca ^ lm) << 4));
    }

  // ---- loop-invariant offsets ----
  unsigned aoff[4][4];   // [kg 0..3][ii]
  #pragma unroll
  for (int kg = 0; kg < 4; kg++)
    #pragma unroll
    for (int ii = 0; ii < 4; ii++){
      const int m = wy * 64 + ii * 16 + lm;
      const int ca = kg * 4 + l4;
      aoff[kg][ii] = (unsigned)(m * 512 + ((ca ^ lm) << 4));
    }
  unsigned boffb[2][2];  // [ks2][jj], ring offset added at use
  #pragma unroll
  for (int q = 0; q < 2; q++)
    #pragma unroll
    for (int jj = 0; jj < 2; jj++){
      const int n = wx * 32 + jj * 16 + lm;
      const int c2 = q * 4 + l4;
      boffb[q][jj] = (unsigned)(n * 128 + ((c2 ^ (n & 7)) << 4));
    }

  // ---- stage state: next slice = 3, ring 3 ----
  int r_st = 3, st_cc = 0, st_ss = 3;
  auto stageB = [&](){
    const size_t soff = (size_t)st_cc * 65536 + (unsigned)(st_ss * 128);
    char* dst = (char*)Bs + ((unsigned)r_st << 14);
    g2lds16(gB0 + soff, dst + dst0);
    g2lds16(gB1 + soff, dst + dst1);
    r_st = (r_st == 4) ? 0 : r_st + 1;
    st_ss++; if (st_ss == 4){ st_ss = 0; st_cc++; }
  };

  unsigned k1[16], k2[16];
  #pragma unroll
  for (int i = 0; i < 16; i++){ k1[i] = 0xFFFFFFFFu; k2[i] = 0xFFFFFFFFu; }

  f32x4 acc[4][2];
  int r_rd = 0;

#define VMW_(n) asm volatile("s_waitcnt vmcnt(" #n ")" ::: "memory")
#define VMW(n) VMW_(n)

#define DSTEP(s_, VM_, ST_) {                                                  \
  const unsigned rb = (unsigned)r_rd << 14;                                    \
  bf16x8 bf[2][2];                                                             \
  _Pragma("unroll")                                                            \
  for (int q = 0; q < 2; q++)                                                  \
    _Pragma("unroll")                                                          \
    for (int jj = 0; jj < 2; jj++)                                             \
      bf[q][jj] = *(const bf16x8*)((const char*)Bs + rb + boffb[q][jj]);       \
  bf16x8 af[2][4];                                                             \
  if (s_ < 2){                                                                 \
    _Pragma("unroll")                                                          \
    for (int q = 0; q < 2; q++)                                                \
      _Pragma("unroll")                                                        \
      for (int ii = 0; ii < 4; ii++)                                           \
        af[q][ii] = *(const bf16x8*)((const char*)A1 + aoff[s_ * 2 + q][ii]);  \
  }                                                                            \
  if (ST_){ stageB(); }                                                        \
  VMW(VM_);                                                                    \
  asm volatile("s_barrier" ::: "memory");                                      \
  if (s_ == 0){                                                                \
    _Pragma("unroll")                                                          \
    for (int ii = 0; ii < 4; ii++)                                             \
      _Pragma("unroll")                                                        \
      for (int jj = 0; jj < 2; jj++)                                           \
        acc[ii][jj] = (f32x4){0.f, 0.f, 0.f, 0.f};                             \
  }                                                                            \
  __builtin_amdgcn_s_setprio(1);                                               \
  _Pragma("unroll")                                                            \
  for (int q = 0; q < 2; q++){                                                 \
    _Pragma("unroll")                                                          \
    for (int ii = 0; ii < 4; ii++)                                             \
      _Pragma("unroll")                                                        \
      for (int jj = 0; jj < 2; jj++)                                           \
        acc[ii][jj] = __builtin_amdgcn_mfma_f32_16x16x32_bf16(                 \
            (s_ < 2) ? af[q][ii] : a2[s_ * 2 + q - 4][ii], bf[q][jj],          \
            acc[ii][jj], 0, 0, 0);                                             \
  }                                                                            \
  __builtin_amdgcn_s_setprio(0);                                               \
  if (s_ == 3){                                                                \
    _Pragma("unroll")                                                          \
    for (int ii = 0; ii < 4; ii++)                                             \
      _Pragma("unroll")                                                        \
      for (int r = 0; r < 4; r++){                                             \
        const int rk = ii * 4 + r;                                             \
        const float v0 = fmaf(-2.f, acc[ii][0][r], 0.125f);                    \
        const float v1 = fmaf(-2.f, acc[ii][1][r], 0.125f);                    \
        const unsigned kb0 = (__float_as_uint(v0) & 0xFFFFFF80u) | pk0;        \
        const unsigned kb1 = (__float_as_uint(v1) & 0xFFFFFF80u) | pk1;        \
        const unsigned lo = umin2(kb0, kb1), hi = umax2(kb0, kb1);             \
        const unsigned tm = umax2(k1[rk], lo);                                 \
        k1[rk] = umin2(k1[rk], lo);                                            \
        k2[rk] = umin2(umin2(k2[rk], tm), hi);                                 \
      }                                                                        \
  }                                                                            \
  r_rd = (r_rd == 4) ? 0 : r_rd + 1;                                           \
}

  for (int c = 0; c < 31; c++){
    const unsigned pk0 = (unsigned)(c * 2), pk1 = pk0 + 1;
    DSTEP(0, 4, 1)
    DSTEP(1, 4, 1)
    DSTEP(2, 4, 1)
    DSTEP(3, 4, 1)
  }
  {
    const unsigned pk0 = 62u, pk1 = 63u;
    DSTEP(0, 4, 1)   // S=124: stages slice 127
    DSTEP(1, 2, 0)   // S=125: need stage(126) landed
    DSTEP(2, 0, 0)   // S=126: need stage(127) landed
    DSTEP(3, 0, 0)   // S=127: nothing outstanding
  }
#undef DSTEP
#undef VMW
#undef VMW_

  // ---- finalize keys to (qi<<12)|col; 2-stage merge: top-8 of 128 per row ----
  __syncthreads();
  const unsigned colpart = (unsigned)(wx * 32 + lm);
  auto fin = [colpart](unsigned key)->unsigned {
    const float v = __uint_as_float(key & 0xFFFFFF80u);
    int qi = (int)(v * 4194304.f);             // (0.125 - 2s) * 2^22
    qi = qi < 0 ? 0 : (qi > 0xFFFFF ? 0xFFFFF : qi);
    const unsigned cc = (key >> 1) & 31u, jj = key & 1u;
    return ((unsigned)qi << 12) | ((cc << 7) + (jj << 4) + colpart);
  };
  unsigned* red = (unsigned*)&A1[0];        // 64 KB = [128 rows][128 entries]
  #pragma unroll
  for (int rk = 0; rk < 16; rk++){
    const int srow = wy * 64 + (rk >> 2) * 16 + l4 * 4 + (rk & 3);
    red[srow * 128 + wx * 32 + lm * 2 + 0] = fin(k1[rk]);
    red[srow * 128 + wx * 32 + lm * 2 + 1] = fin(k2[rk]);
  }
  __syncthreads();
  unsigned* red2 = (unsigned*)&Bs[0][0];    // 16 KB = [128 rows][32]
  {
    const int row = tid >> 2, seg = tid & 3;
    unsigned best[8];
    #pragma unroll
    for (int j = 0; j < 8; j++) best[j] = 0xFFFFFFFFu;
    const unsigned* rp = red + row * 128 + seg * 32;
    for (int i = 0; i < 32; i++){
      unsigned kk = rp[i];
      if (kk < best[7]){
        best[7] = kk;
        #pragma unroll
        for (int j = 7; j > 0; j--)
          if (best[j] < best[j-1]){ unsigned tmp = best[j]; best[j] = best[j-1]; best[j-1] = tmp; }
      }
    }
    #pragma unroll
    for (int j = 0; j < 8; j++) red2[row * 32 + seg * 8 + j] = best[j];
  }
  __syncthreads();
  if (tid < 128){
    unsigned best[8];
    #pragma unroll
    for (int j = 0; j < 8; j++) best[j] = 0xFFFFFFFFu;
    const unsigned* rp = red2 + tid * 32;
    for (int i = 0; i < 32; i++){
      unsigned kk = rp[i];
      if (kk < best[7]){
        best[7] = kk;
        #pragma unroll
        for (int j = 7; j > 0; j--)
          if (best[j] < best[j-1]){ unsigned tmp = best[j]; best[j] = best[j-1]; best[j-1] = tmp; }
      }
    }
    const size_t base = ((size_t)(tok0 + tid) * 2 + h) * 8;
    #pragma unroll
    for (int j = 0; j < 8; j++) cand[base + j] = h * 4096 + (int)(best[j] & 0xFFFu);
  }
}

// ========== phase 2: np-fp32-semantics rescore (one wave / token) ==========
// fused: histogram atomicAdd + float index output
__global__ void k_pick(const float* __restrict__ x, const float* __restrict__ cb,
                       const float* __restrict__ a32, const float* __restrict__ b32,
                       const int* __restrict__ cand, int* __restrict__ idx,
                       int* __restrict__ icnt, float* __restrict__ out_idx)
{
  const int gt = blockIdx.x * 256 + threadIdx.x;
  const int n = gt >> 6;
  const int lane = gt & 63;
  const int b = n >> 10, hw = n & 1023;
  const int c0 = lane * 4;
  float z0 = x[(((size_t)b * DIM + c0 + 0) << 10) + hw];
  float z1 = x[(((size_t)b * DIM + c0 + 1) << 10) + hw];
  float z2 = x[(((size_t)b * DIM + c0 + 2) << 10) + hw];
  float z3 = x[(((size_t)b * DIM + c0 + 3) << 10) + hw];
  const float an = a32[n];
  float bestd = 3.4e38f; int besti = 0x7fffffff;
  for (int j = 0; j < 16; j++){
    const int ci = cand[(size_t)n * 16 + j];
    if (ci < 0 || ci >= KCB) continue;
    float4 e = *(const float4*)(cb + (size_t)ci * DIM + c0);
    double se = (double)z0*e.x + (double)z1*e.y + (double)z2*e.z + (double)z3*e.w;
    #pragma unroll
    for (int o = 32; o > 0; o >>= 1) se += __shfl_xor(se, o, 64);
    const float A = an + b32[ci];
    const float d32 = (float)((double)A - 2.0 * se);
    if (d32 < bestd || (d32 == bestd && ci < besti)){ bestd = d32; besti = ci; }
  }
  if (lane == 0){
    idx[n] = besti;
    atomicAdd(icnt + besti, 1);
    out_idx[n] = (float)besti;
  }
}

// ===================== exclusive scan of 8192 counts (1 block) =====================
__global__ void k_scan(const int* __restrict__ icnt, int* __restrict__ offs){
  __shared__ int sums[256];
  const int tid = threadIdx.x;
  int loc[32];
  int s = 0;
  #pragma unroll
  for (int i = 0; i < 32; i++){ loc[i] = s; s += icnt[tid * 32 + i]; }
  sums[tid] = s;
  #pragma unroll
  for (int off = 1; off < 256; off <<= 1){
    __syncthreads();
    const int add = (tid >= off) ? sums[tid - off] : 0;
    __syncthreads();
    sums[tid] += add;
  }
  __syncthreads();
  const int pre = (tid == 0) ? 0 : sums[tid - 1];
  #pragma unroll
  for (int i = 0; i < 32; i++) offs[tid * 32 + i] = pre + loc[i];
}

// ===================== bucket tokens by code =====================
__global__ void k_perm(const int* __restrict__ idx, const int* __restrict__ offs,
                       int* __restrict__ cur, int* __restrict__ perm){
  int t = blockIdx.x * 256 + threadIdx.x;     // 32,768
  int code = idx[t];
  int slot = atomicAdd(cur + code, 1);
  perm[offs[code] + slot] = t;
}

// ===================== dw segment-sum: one block per code, no atomics ==========
__global__ void k_dw(const unsigned short* __restrict__ flatB,
                     const int* __restrict__ offs, const int* __restrict__ icnt,
                     const int* __restrict__ perm, float* __restrict__ dw)
{
  const int k = blockIdx.x;                   // 8192
  const int c = threadIdx.x;                  // 256
  const int start = offs[k], cnt = icnt[k];
  float s = 0.f;
  for (int i = 0; i < cnt; i++){
    const int n = perm[start + i];
    s += __uint_as_float(((unsigned)flatB[((size_t)n << 8) + c]) << 16);
  }
  dw[((size_t)k << 8) + c] = s;               // empty code -> exact 0.0
}

// ===================== quantize + loss partials (NO atomics) =====================
__global__ void k_quant(const float* __restrict__ x, const float* __restrict__ cb,
                        const int* __restrict__ idx, float* __restrict__ outq,
                        double* __restrict__ lpart)
{
  __shared__ double wred[4];
  int t = blockIdx.x * 256 + threadIdx.x;     // 2,097,152
  int c = t >> 13;
  int g = t & 8191; int n = g * 4;
  int b = n >> 10, hw = n & 1023;
  size_t xo = (((size_t)b * DIM + c) << 10) + hw;
  float4 xv = *(const float4*)(x + xo);
  int i0 = idx[n], i1 = idx[n+1], i2 = idx[n+2], i3 = idx[n+3];
  float q0 = cb[(size_t)i0 * DIM + c];
  float q1 = cb[(size_t)i1 * DIM + c];
  float q2 = cb[(size_t)i2 * DIM + c];
  float q3 = cb[(size_t)i3 * DIM + c];
  float qd0 = q0 - xv.x, qd1 = q1 - xv.y, qd2 = q2 - xv.z, qd3 = q3 - xv.w;
  float4 ov = { xv.x + qd0, xv.y + qd1, xv.z + qd2, xv.w + qd3 };
  *(float4*)(outq + xo) = ov;                 // xo is 16B-aligned (hw % 4 == 0)
  double p = (double)(qd0*qd0 + qd1*qd1 + qd2*qd2 + qd3*qd3);
  #pragma unroll
  for (int o = 32; o > 0; o >>= 1) p += __shfl_down(p, o, 64);
  if ((threadIdx.x & 63) == 0) wred[threadIdx.x >> 6] = p;
  __syncthreads();
  if (threadIdx.x == 0) lpart[blockIdx.x] = (wred[0] + wred[1]) + (wred[2] + wred[3]);
}

// ===================== new_count + e_loss (block 0 reduces loss partials) ==========
__global__ void k_count(const int* __restrict__ icnt, const float* __restrict__ ema_count,
                        const double* __restrict__ lpart, float* __restrict__ out)
{
  int k = blockIdx.x * 256 + threadIdx.x;     // 8,192
  float t1 = ema_count[k] * 0.95f;
  float t2 = 0.05f * (float)icnt[k];
  float s  = t1 + t2;
  float s2 = s + 1e-5f;
  const float DEN = (float)(32768.0 + 8192.0 * 1e-5);
  float nc = (s2 / DEN) * 32768.0f;
  out[O_CNT + k] = nc;
  if (blockIdx.x == 0){
    __shared__ double sred[256];
    const int tid = threadIdx.x;
    double ls = 0.0;
    for (int i = tid; i < 8192; i += 256) ls += lpart[i];
    sred[tid] = ls;
    __syncthreads();
    for (int off = 128; off > 0; off >>= 1){
      if (tid < off) sred[tid] += sred[tid + off];
      __syncthreads();
    }
    if (tid == 0) out[O_LOSS] = 0.25f * (float)(sred[0] / 8388608.0);
  }
}

// ===================== new_weight + new_codebook =====================
__global__ void k_final(const float* __restrict__ ema_w, const float* __restrict__ dw,
                        const float* __restrict__ out_cnt,
                        float* __restrict__ out_w, float* __restrict__ out_cb)
{
  #pragma clang fp contract(off)
  int t = blockIdx.x * 256 + threadIdx.x;     // 2,097,152
  int k = t >> 8;
  float w = ema_w[t];
  float d = dw[t];
  float t1 = w * 0.95f;
  float t2 = 0.05f * d;
  float nw = t1 + t2;          // np op order; bit-exact for empty codes (d==0)
  out_w[t]  = nw;
  out_cb[t] = nw / out_cnt[k];
}

// ===================== launch =====================
extern "C" void kernel_launch(void* const* d_in, const int* in_sizes, int n_in,
                              void* d_out, int out_size, void* d_ws, size_t ws_size,
                              hipStream_t stream)
{
  const float* x         = (const float*)d_in[0];
  const float* cb        = (const float*)d_in[1];
  const float* ema_count = (const float*)d_in[2];
  const float* ema_w     = (const float*)d_in[3];
  float* out = (float*)d_out;
  float* ws  = (float*)d_ws;

  unsigned short* flatB = (unsigned short*)(ws + WS_FLATB);
  unsigned short* cbB   = (unsigned short*)(ws + WS_CBB);
  float*  a32    = ws + WS_A32;
  float*  b32    = ws + WS_B32;
  int*    idxp   = (int*)(ws + WS_IDX);
  int*    candp  = (int*)(ws + WS_CAND);
  int*    icnt   = (int*)(ws + WS_ICNT);
  int*    curp   = (int*)(ws + WS_CUR);
  int*    offs   = (int*)(ws + WS_OFFS);
  int*    permp  = (int*)(ws + WS_PERM);
  double* lpart  = (double*)(ws + WS_LPART);
  float*  dwp    = ws + WS_DW;

  (void)hipMemsetAsync(ws + WS_ICNT, 0, (size_t)WS_MEMSET_LEN * sizeof(float), stream);

  k_flatb<<<2048, 256, 0, stream>>>(x, flatB);
  k_cbb  <<<2048, 256, 0, stream>>>(cb, cbB);
  k_sqn  <<<160,  256, 0, stream>>>(x, cb, a32, b32);
  k_dist <<<512,  512, 0, stream>>>(flatB, cbB, candp);
  k_pick <<<8192, 256, 0, stream>>>(x, cb, a32, b32, candp, idxp, icnt, out + O_IDX);
  k_scan <<<1,    256, 0, stream>>>(icnt, offs);
  k_perm <<<128,  256, 0, stream>>>(idxp, offs, curp, permp);
  k_dw   <<<8192, 256, 0, stream>>>(flatB, offs, icnt, permp, dwp);
  k_quant<<<8192, 256, 0, stream>>>(x, cb, idxp, out + O_Q, lpart);
  k_count<<<32,   256, 0, stream>>>(icnt, ema_count, lpart, out);
  k_final<<<8192, 256, 0, stream>>>(ema_w, dwp, out + O_CNT, out + O_W, out + O_CB);
}

// Round 4
// 411.377 us; speedup vs baseline: 1.1247x; 1.1247x over previous
//
#include <hip/hip_runtime.h>
#include <stdint.h>

// Problem constants
#define N_TOK 32768   // B*H*W tokens
#define DIM   256
#define KCB   8192
#define HWSZ  1024

// ---- workspace layout (float offsets) ---- total 8,011,776 floats = 32.0 MB
#define WS_FLATB   0u          // bf16 flat [32768][256]  (4,194,304)
#define WS_CBB     4194304u    // bf16 cb [8192][256]     (1,048,576)
#define WS_A32     5242880u    // np-fp32 ||z||^2         32,768
#define WS_B32     5275648u    // np-fp32 ||e||^2         8,192
#define WS_IDX     5283840u    // argmin (int)            32,768
#define WS_CAND    5316608u    // [token][16] int         524,288
#define WS_ICNT    5840896u    // int histogram           8,192   <- memset from here
#define WS_CUR     5849088u    // int cursors             8,192   <- memset through here
#define WS_OFFS    5857280u    // int exclusive offsets   8,192
#define WS_PERM    5865472u    // int token permutation   32,768
#define WS_LPART   5898240u    // per-block loss partials 2,048 doubles (4,096 floats)
#define WS_DW      5914624u    // segment-sum fp32        2,097,152
#define WS_TOTAL   8011776u
#define WS_MEMSET_LEN 16384u   // ICNT + CUR only

// ---- output layout (float offsets) ----
#define O_LOSS 0u
#define O_Q    1u
#define O_IDX  8388609u
#define O_CNT  8421377u
#define O_W    8429569u
#define O_CB   10526721u

typedef __attribute__((ext_vector_type(8))) short bf16x8;
typedef __attribute__((ext_vector_type(4))) float f32x4;

__device__ __forceinline__ void g2lds16(const void* gp, void* lp){
  __builtin_amdgcn_global_load_lds(
      (const __attribute__((address_space(1))) void*)gp,
      (__attribute__((address_space(3))) void*)lp, 16, 0, 0);
}

__device__ __forceinline__ unsigned short f2b(float f){   // fp32 -> bf16 RNE
  unsigned u = __float_as_uint(f);
  return (unsigned short)((u + 0x7FFFu + ((u >> 16) & 1u)) >> 16);
}

__device__ __forceinline__ unsigned umin2(unsigned a, unsigned b){ return a < b ? a : b; }
__device__ __forceinline__ unsigned umax2(unsigned a, unsigned b){ return a > b ? a : b; }

// ============ prep: squared norms, numpy pairwise fp32 order ============
__device__ __forceinline__ float np_pairwise_sq(const float* __restrict__ p, int stride){
  #pragma clang fp contract(off)
  float h[2];
  #pragma unroll
  for (int half = 0; half < 2; half++){
    const float* q = p + half * 128 * stride;
    float r[8];
    #pragma unroll
    for (int j = 0; j < 8; j++){ float z = q[j * stride]; r[j] = z * z; }
    for (int i = 8; i < 128; i += 8){
      #pragma unroll
      for (int j = 0; j < 8; j++){ float z = q[(i + j) * stride]; r[j] = r[j] + z * z; }
    }
    h[half] = ((r[0] + r[1]) + (r[2] + r[3])) + ((r[4] + r[5]) + (r[6] + r[7]));
  }
  return h[0] + h[1];
}

// ============ fused prep: flatb transpose | cb->bf16 | squared norms ============
// blocks [0,2048): x [B,C,H,W] -> flatB bf16 [token][c]
// blocks [2048,4096): codebook fp32 -> bf16
// blocks [4096,4256): a32 / b32 norms (numpy pairwise order)
__global__ void k_prep(const float* __restrict__ x, const float* __restrict__ cb,
                       unsigned short* __restrict__ flatB, unsigned short* __restrict__ cbB,
                       float* __restrict__ a32, float* __restrict__ b32)
{
  __shared__ float tile[64][65];
  const int bx = blockIdx.x;
  const int t = threadIdx.x;
  if (bx < 2048){
    const int b = bx >> 6, ct = (bx >> 4) & 3, ht = bx & 15;
    const int c0 = ct * 64, hw0 = ht * 64;
    const int rr = t >> 4, cc4 = (t & 15) * 4;
    #pragma unroll
    for (int j = 0; j < 4; j++){
      const int crow = rr + j * 16;
      float4 v = *(const float4*)(x + ((size_t)(b * 256 + c0 + crow) << 10) + hw0 + cc4);
      tile[crow][cc4] = v.x; tile[crow][cc4+1] = v.y; tile[crow][cc4+2] = v.z; tile[crow][cc4+3] = v.w;
    }
    __syncthreads();
    #pragma unroll
    for (int j = 0; j < 4; j++){
      const int hwrow = rr + j * 16;
      ushort4 o = { f2b(tile[cc4][hwrow]), f2b(tile[cc4+1][hwrow]),
                    f2b(tile[cc4+2][hwrow]), f2b(tile[cc4+3][hwrow]) };
      *(ushort4*)(flatB + ((size_t)(b * 1024 + hw0 + hwrow) << 8) + c0 + cc4) = o;
    }
  } else if (bx < 4096){
    const int g = (bx - 2048) * 256 + t;    // 524,288
    float4 v = *(const float4*)(cb + (size_t)g * 4);
    ushort4 o = { f2b(v.x), f2b(v.y), f2b(v.z), f2b(v.w) };
    *(ushort4*)(cbB + (size_t)g * 4) = o;
  } else {
    const int g = (bx - 4096) * 256 + t;    // 40,960
    if (g < N_TOK){
      int b = g >> 10, hw = g & 1023;
      a32[g] = np_pairwise_sq(x + (size_t)b * 262144 + hw, 1024);
    } else {
      int k2 = g - N_TOK;
      b32[k2] = np_pairwise_sq(cb + (size_t)k2 * 256, 1);
    }
  }
}

// ============ phase 1: bf16-MFMA distance GEMM + top-8 candidates/half ============
// (reverted to best-measured variant: 155.5us. VALU-diet keys, loop-invariant
//  addresses, 2-buffer staging with draining __syncthreads per S-step.)
__launch_bounds__(256, 2)
__global__ void k_dist(const unsigned short* __restrict__ flatB,
                       const unsigned short* __restrict__ cbB,
                       const float* __restrict__ b32,
                       int* __restrict__ cand)
{
  __shared__ __align__(16) unsigned short A1[128 * 128];   // 32 KB: [row][k0..127]
  __shared__ __align__(16) unsigned short Bs[2][128 * 64]; // 2 x 16 KB

  const int tid = threadIdx.x;
  const int bx = blockIdx.x;             // 512 = 256 token-tiles x 2 halves
  const int tt = bx >> 1, h = bx & 1;
  const int tok0 = tt * 128;
  const int wv = tid >> 6, lane = tid & 63;
  const int wy = wv >> 1, wx = wv & 1;
  const int l4 = lane >> 4, lm = lane & 15;

  const unsigned short* fB = flatB + (size_t)tok0 * 256;
  const unsigned short* cB = cbB + (size_t)h * 4096 * 256;

  // ---- stage A1 (k 0..127) and A2 (k 128..255, into Bs region) ----
  {
    const int r = lane >> 4, p = lane & 15;
    #pragma unroll
    for (int j = 0; j < 8; j++){
      const int row = wv * 32 + j * 4 + r;
      const int gc = p ^ (row & 15);
      g2lds16((const char*)fB + (size_t)row * 512 + (gc << 4),
              (char*)A1 + (wv * 32 + j * 4) * 256);
    }
    unsigned short* A2 = &Bs[0][0];
    #pragma unroll
    for (int j = 0; j < 8; j++){
      const int row = wv * 32 + j * 4 + r;
      const int gc = p ^ (row & 15);
      g2lds16((const char*)fB + (size_t)row * 512 + 256 + (gc << 4),
              (char*)A2 + (wv * 32 + j * 4) * 256);
    }
  }
  __syncthreads();

  // ---- A k128..255 fragments -> registers (16 x b128 = 64 VGPR) ----
  bf16x8 a2[4][4];
  {
    const unsigned short* A2 = &Bs[0][0];
    #pragma unroll
    for (int ks4 = 0; ks4 < 4; ks4++)
      #pragma unroll
      for (int ii = 0; ii < 4; ii++){
        const int m = wy * 64 + ii * 16 + lm;
        const int c = ks4 * 4 + l4;
        a2[ks4][ii] = *(const bf16x8*)((const char*)A2 + m * 256 + ((c ^ (m & 15)) << 4));
      }
  }
  __syncthreads();   // A2 regs loaded; Bs region now reusable for B slices

  // ---- loop-invariant address precompute ----
  unsigned aoff[4][4];   // [kg 0..3][ii] byte offsets into A1
  #pragma unroll
  for (int kg = 0; kg < 4; kg++)
    #pragma unroll
    for (int ii = 0; ii < 4; ii++){
      const int m = wy * 64 + ii * 16 + lm;
      const int ca = kg * 4 + l4;
      aoff[kg][ii] = (unsigned)(m * 256 + ((ca ^ (m & 15)) << 4));
    }
  unsigned boff[2][2][4];  // [buf][ks2][jj] byte offsets into Bs
  #pragma unroll
  for (int buf = 0; buf < 2; buf++)
    #pragma unroll
    for (int ks2 = 0; ks2 < 2; ks2++)
      #pragma unroll
      for (int jj = 0; jj < 4; jj++){
        const int n = wx * 64 + jj * 16 + lm;
        const int c2 = ks2 * 4 + l4;
        boff[buf][ks2][jj] = (unsigned)(buf * 16384 + n * 128 + ((c2 ^ (n & 7)) << 4));
      }
  // stageB per-lane invariants
  const char* gBj[4];
  unsigned dstj[4];
  {
    const int r8 = lane >> 3, p = lane & 7;
    #pragma unroll
    for (int j = 0; j < 4; j++){
      const int row = wv * 32 + j * 8 + r8;
      const int gc = p ^ (row & 7);
      gBj[j] = (const char*)cB + (size_t)row * 512 + (gc << 4);
      dstj[j] = (unsigned)((wv * 32 + j * 8) * 128);
    }
  }

  auto stageB = [&](int S2){
    const int ss = S2 & 3, cc = S2 >> 2;
    const int buf = (S2 & 1) * 16384;
    const size_t soff = (size_t)(cc * 65536 + ss * 128);   // scalar (wave-uniform)
    #pragma unroll
    for (int j = 0; j < 4; j++)
      g2lds16(gBj[j] + soff, (char*)Bs + buf + dstj[j]);
  };

  unsigned k1[16], k2[16];
  #pragma unroll
  for (int i = 0; i < 16; i++){ k1[i] = 0xFFFFFFFFu; k2[i] = 0xFFFFFFFFu; }

  f32x4 acc[4][4];
  float bn125[4];

  stageB(0);
  __syncthreads();

  for (int c = 0; c < 32; c++){
    #pragma unroll
    for (int s = 0; s < 4; s++){
      const int S = c * 4 + s;
      if (S + 1 < 128) stageB(S + 1);
      if (s == 0){
        #pragma unroll
        for (int jj = 0; jj < 4; jj++)
          bn125[jj] = b32[h * 4096 + c * 128 + wx * 64 + jj * 16 + lm] + 0.125f;
        #pragma unroll
        for (int ii = 0; ii < 4; ii++)
          #pragma unroll
          for (int jj = 0; jj < 4; jj++)
            acc[ii][jj] = (f32x4){0.f, 0.f, 0.f, 0.f};
      }
      #pragma unroll
      for (int ks2 = 0; ks2 < 2; ks2++){
        const int kg = s * 2 + ks2;          // 0..7 (compile-time)
        bf16x8 bf[4], af[4];
        #pragma unroll
        for (int jj = 0; jj < 4; jj++)
          bf[jj] = *(const bf16x8*)((const char*)Bs + boff[s & 1][ks2][jj]);
        if (kg < 4){
          #pragma unroll
          for (int ii = 0; ii < 4; ii++)
            af[ii] = *(const bf16x8*)((const char*)A1 + aoff[kg][ii]);
        } else {
          #pragma unroll
          for (int ii = 0; ii < 4; ii++) af[ii] = a2[kg - 4][ii];
        }
        #pragma unroll
        for (int ii = 0; ii < 4; ii++)
          #pragma unroll
          for (int jj = 0; jj < 4; jj++)
            acc[ii][jj] = __builtin_amdgcn_mfma_f32_16x16x32_bf16(af[ii], bf[jj], acc[ii][jj], 0, 0, 0);
      }
      if (s == 3){
        // rank by float bits of (b - 2s + 0.125) > 0; (c<<2)|jj packed in low 7 bits
        unsigned pk[4];
        #pragma unroll
        for (int jj = 0; jj < 4; jj++) pk[jj] = (unsigned)((c << 2) | jj);
        #pragma unroll
        for (int ii = 0; ii < 4; ii++){
          #pragma unroll
          for (int r = 0; r < 4; r++){
            const int rk = ii * 4 + r;
            unsigned kb[4];
            #pragma unroll
            for (int jj = 0; jj < 4; jj++){
              const float v = fmaf(-2.f, acc[ii][jj][r], bn125[jj]);
              kb[jj] = (__float_as_uint(v) & 0xFFFFFF80u) | pk[jj];
            }
            // smallest-2-of-4
            const unsigned lo01 = umin2(kb[0], kb[1]), hi01 = umax2(kb[0], kb[1]);
            const unsigned lo23 = umin2(kb[2], kb[3]), hi23 = umax2(kb[2], kb[3]);
            const unsigned s1 = umin2(lo01, lo23);
            const unsigned s2 = umin2(umax2(lo01, lo23), umin2(hi01, hi23));
            // merge two sorted pairs (k1,k2) x (s1,s2) -> top-2
            const unsigned t = umax2(k1[rk], s1);
            k1[rk] = umin2(k1[rk], s1);
            k2[rk] = umin2(umin2(k2[rk], t), s2);
          }
        }
      }
      __syncthreads();
    }
  }

  // ---- finalize keys to (qi<<12)|col and merge: per row, top-8 of 64 keys ----
  const unsigned colbase = (unsigned)(wx * 64 + lm);
  auto fin = [colbase](unsigned key)->unsigned {
    const float v125 = __uint_as_float(key & 0xFFFFFF80u);
    int qi = (int)(v125 * 4194304.f);          // (v + 0.125) * 2^22
    qi = qi < 0 ? 0 : (qi > 0xFFFFF ? 0xFFFFF : qi);
    const unsigned cc = (key >> 2) & 31u, jj = key & 3u;
    return ((unsigned)qi << 12) | (cc * 128u + jj * 16u + colbase);
  };
  unsigned* red = (unsigned*)&A1[0];        // 32 KB = 8192 u32 = [128 rows][64]
  #pragma unroll
  for (int rk = 0; rk < 16; rk++){
    const int srow = wy * 64 + (rk >> 2) * 16 + l4 * 4 + (rk & 3);
    red[srow * 64 + wx * 32 + lm * 2 + 0] = fin(k1[rk]);
    red[srow * 64 + wx * 32 + lm * 2 + 1] = fin(k2[rk]);
  }
  __syncthreads();
  if (tid < 128){
    unsigned best[8];
    #pragma unroll
    for (int j = 0; j < 8; j++) best[j] = 0xFFFFFFFFu;
    for (int i = 0; i < 64; i++){
      unsigned k = red[tid * 64 + i];
      if (k < best[7]){
        best[7] = k;
        #pragma unroll
        for (int j = 7; j > 0; j--){
          if (best[j] < best[j-1]){ unsigned tmp = best[j]; best[j] = best[j-1]; best[j-1] = tmp; }
        }
      }
    }
    const size_t base = ((size_t)(tok0 + tid) * 2 + h) * 8;
    #pragma unroll
    for (int j = 0; j < 8; j++) cand[base + j] = h * 4096 + (int)(best[j] & 0xFFFu);
  }
}

// ========== phase 2: np-fp32-semantics rescore (one wave / token) ==========
// fused: histogram atomicAdd + float index output
__global__ void k_pick(const float* __restrict__ x, const float* __restrict__ cb,
                       const float* __restrict__ a32, const float* __restrict__ b32,
                       const int* __restrict__ cand, int* __restrict__ idx,
                       int* __restrict__ icnt, float* __restrict__ out_idx)
{
  const int gt = blockIdx.x * 256 + threadIdx.x;
  const int n = gt >> 6;
  const int lane = gt & 63;
  const int b = n >> 10, hw = n & 1023;
  const int c0 = lane * 4;
  float z0 = x[(((size_t)b * DIM + c0 + 0) << 10) + hw];
  float z1 = x[(((size_t)b * DIM + c0 + 1) << 10) + hw];
  float z2 = x[(((size_t)b * DIM + c0 + 2) << 10) + hw];
  float z3 = x[(((size_t)b * DIM + c0 + 3) << 10) + hw];
  const float an = a32[n];
  float bestd = 3.4e38f; int besti = 0x7fffffff;
  for (int j = 0; j < 16; j++){
    const int ci = cand[(size_t)n * 16 + j];
    if (ci < 0 || ci >= KCB) continue;
    float4 e = *(const float4*)(cb + (size_t)ci * DIM + c0);
    double se = (double)z0*e.x + (double)z1*e.y + (double)z2*e.z + (double)z3*e.w;
    #pragma unroll
    for (int o = 32; o > 0; o >>= 1) se += __shfl_xor(se, o, 64);
    const float A = an + b32[ci];
    const float d32 = (float)((double)A - 2.0 * se);
    if (d32 < bestd || (d32 == bestd && ci < besti)){ bestd = d32; besti = ci; }
  }
  if (lane == 0){
    idx[n] = besti;
    atomicAdd(icnt + besti, 1);
    out_idx[n] = (float)besti;
  }
}

// ===================== exclusive scan of 8192 counts (1 block) =====================
__global__ void k_scan(const int* __restrict__ icnt, int* __restrict__ offs){
  __shared__ int sums[256];
  const int tid = threadIdx.x;
  int loc[32];
  int s = 0;
  #pragma unroll
  for (int i = 0; i < 32; i++){ loc[i] = s; s += icnt[tid * 32 + i]; }
  sums[tid] = s;
  #pragma unroll
  for (int off = 1; off < 256; off <<= 1){
    __syncthreads();
    const int add = (tid >= off) ? sums[tid - off] : 0;
    __syncthreads();
    sums[tid] += add;
  }
  __syncthreads();
  const int pre = (tid == 0) ? 0 : sums[tid - 1];
  #pragma unroll
  for (int i = 0; i < 32; i++) offs[tid * 32 + i] = pre + loc[i];
}

// ===================== bucket tokens by code =====================
__global__ void k_perm(const int* __restrict__ idx, const int* __restrict__ offs,
                       int* __restrict__ cur, int* __restrict__ perm){
  int t = blockIdx.x * 256 + threadIdx.x;     // 32,768
  int code = idx[t];
  int slot = atomicAdd(cur + code, 1);
  perm[offs[code] + slot] = t;
}

// ===================== dw segment-sum: one block per code, no atomics ==========
__global__ void k_dw(const unsigned short* __restrict__ flatB,
                     const int* __restrict__ offs, const int* __restrict__ icnt,
                     const int* __restrict__ perm, float* __restrict__ dw)
{
  const int k = blockIdx.x;                   // 8192
  const int c = threadIdx.x;                  // 256
  const int start = offs[k], cnt = icnt[k];
  float s = 0.f;
  for (int i = 0; i < cnt; i++){
    const int n = perm[start + i];
    s += __uint_as_float(((unsigned)flatB[((size_t)n << 8) + c]) << 16);
  }
  dw[((size_t)k << 8) + c] = s;               // empty code -> exact 0.0
}

// ===================== quantize + loss partials (LDS-tiled cb gather) ==========
// block = one (64c x 64hw) tile: 2048 blocks. cb rows for the tile's 64 tokens
// gathered ONCE each as coalesced 256B row-segments into LDS (vs per-element
// column gather: ~16x less cache-line traffic). x read / outq write stay
// float4-coalesced over hw. Per-element arithmetic identical: ov = x + (q - x).
__global__ void k_quant(const float* __restrict__ x, const float* __restrict__ cb,
                        const int* __restrict__ idx, float* __restrict__ outq,
                        double* __restrict__ lpart)
{
  __shared__ float qt[64][65];
  __shared__ double wred[4];
  const int bx = blockIdx.x;                  // 2048 = b(32) x ct(4) x ht(16)
  const int tid = threadIdx.x;                // 256
  const int b = bx >> 6, ct = (bx >> 4) & 3, ht = bx & 15;
  const int c0 = ct * 64, hw0 = ht * 64;
  const int n0 = b * 1024 + hw0;

  // gather: wave w fetches rows w,4+w,...,60+w; 64 lanes read 256B of a cb row
  {
    const int cl = tid & 63, wq = tid >> 6;
    for (int r16 = 0; r16 < 16; r16++){
      const int row = r16 * 4 + wq;
      const int i = idx[n0 + row];            // broadcast
      qt[row][cl] = cb[(size_t)i * DIM + c0 + cl];
    }
  }
  __syncthreads();

  const int cc = tid >> 4;                    // 0..15
  const int hw4 = (tid & 15) * 4;
  double p = 0.0;
  #pragma unroll
  for (int j = 0; j < 4; j++){
    const int cl = cc + j * 16;               // 0..63
    const size_t xo = (((size_t)(b * 256 + c0 + cl)) << 10) + hw0 + hw4;
    float4 xv = *(const float4*)(x + xo);
    float q0 = qt[hw4 + 0][cl];
    float q1 = qt[hw4 + 1][cl];
    float q2 = qt[hw4 + 2][cl];
    float q3 = qt[hw4 + 3][cl];
    float qd0 = q0 - xv.x, qd1 = q1 - xv.y, qd2 = q2 - xv.z, qd3 = q3 - xv.w;
    float4 ov = { xv.x + qd0, xv.y + qd1, xv.z + qd2, xv.w + qd3 };
    *(float4*)(outq + xo) = ov;               // 16B-aligned (hw4 % 4 == 0)
    p += (double)(qd0*qd0 + qd1*qd1 + qd2*qd2 + qd3*qd3);
  }
  #pragma unroll
  for (int o = 32; o > 0; o >>= 1) p += __shfl_down(p, o, 64);
  if ((tid & 63) == 0) wred[tid >> 6] = p;
  __syncthreads();
  if (tid == 0) lpart[bx] = (wred[0] + wred[1]) + (wred[2] + wred[3]);
}

// ============ new_weight + new_codebook + new_count + e_loss (fused) ============
// block k handles the 256 weights of code k; nc recomputed locally with the
// exact same fp32 expressions as before. block 0 also reduces the 2048 loss
// partials.
__global__ void k_final(const float* __restrict__ ema_w, const float* __restrict__ dw,
                        const int* __restrict__ icnt, const float* __restrict__ ema_count,
                        const double* __restrict__ lpart, float* __restrict__ out)
{
  const int k = blockIdx.x;                   // 8192
  const int tid = threadIdx.x;                // 256
  float ct1 = ema_count[k] * 0.95f;
  float ct2 = 0.05f * (float)icnt[k];
  float s  = ct1 + ct2;
  float s2 = s + 1e-5f;
  const float DEN = (float)(32768.0 + 8192.0 * 1e-5);
  float nc = (s2 / DEN) * 32768.0f;
  if (tid == 0) out[O_CNT + k] = nc;
  {
    #pragma clang fp contract(off)
    const int t = k * 256 + tid;
    float w = ema_w[t];
    float d = dw[t];
    float t1 = w * 0.95f;
    float t2 = 0.05f * d;
    float nw = t1 + t2;        // np op order; bit-exact for empty codes (d==0)
    out[O_W + t]  = nw;
    out[O_CB + t] = nw / nc;
  }
  if (k == 0){
    __shared__ double sred[256];
    double ls = 0.0;
    for (int i = tid; i < 2048; i += 256) ls += lpart[i];
    sred[tid] = ls;
    __syncthreads();
    for (int off = 128; off > 0; off >>= 1){
      if (tid < off) sred[tid] += sred[tid + off];
      __syncthreads();
    }
    if (tid == 0) out[O_LOSS] = 0.25f * (float)(sred[0] / 8388608.0);
  }
}

// ===================== launch =====================
extern "C" void kernel_launch(void* const* d_in, const int* in_sizes, int n_in,
                              void* d_out, int out_size, void* d_ws, size_t ws_size,
                              hipStream_t stream)
{
  const float* x         = (const float*)d_in[0];
  const float* cb        = (const float*)d_in[1];
  const float* ema_count = (const float*)d_in[2];
  const float* ema_w     = (const float*)d_in[3];
  float* out = (float*)d_out;
  float* ws  = (float*)d_ws;

  unsigned short* flatB = (unsigned short*)(ws + WS_FLATB);
  unsigned short* cbB   = (unsigned short*)(ws + WS_CBB);
  float*  a32    = ws + WS_A32;
  float*  b32    = ws + WS_B32;
  int*    idxp   = (int*)(ws + WS_IDX);
  int*    candp  = (int*)(ws + WS_CAND);
  int*    icnt   = (int*)(ws + WS_ICNT);
  int*    curp   = (int*)(ws + WS_CUR);
  int*    offs   = (int*)(ws + WS_OFFS);
  int*    permp  = (int*)(ws + WS_PERM);
  double* lpart  = (double*)(ws + WS_LPART);
  float*  dwp    = ws + WS_DW;

  (void)hipMemsetAsync(ws + WS_ICNT, 0, (size_t)WS_MEMSET_LEN * sizeof(float), stream);

  k_prep <<<4256, 256, 0, stream>>>(x, cb, flatB, cbB, a32, b32);
  k_dist <<<512,  256, 0, stream>>>(flatB, cbB, b32, candp);
  k_pick <<<8192, 256, 0, stream>>>(x, cb, a32, b32, candp, idxp, icnt, out + O_IDX);
  k_scan <<<1,    256, 0, stream>>>(icnt, offs);
  k_perm <<<128,  256, 0, stream>>>(idxp, offs, curp, permp);
  k_dw   <<<8192, 256, 0, stream>>>(flatB, offs, icnt, permp, dwp);
  k_quant<<<2048, 256, 0, stream>>>(x, cb, idxp, out + O_Q, lpart);
  k_final<<<8192, 256, 0, stream>>>(ema_w, dwp, icnt, ema_count, lpart, out);
}

// Round 5
// 384.873 us; speedup vs baseline: 1.2022x; 1.0689x over previous
//
#include <hip/hip_runtime.h>
#include <stdint.h>

// Problem constants
#define N_TOK 32768   // B*H*W tokens
#define DIM   256
#define KCB   8192
#define HWSZ  1024

// ---- workspace layout (float offsets) ---- total 8,011,776 floats = 32.0 MB
#define WS_FLATB   0u          // bf16 flat [32768][256]  (4,194,304)
#define WS_CBB     4194304u    // bf16 cb [8192][256]     (1,048,576)
#define WS_A32     5242880u    // np-fp32 ||z||^2         32,768
#define WS_B32     5275648u    // np-fp32 ||e||^2         8,192
#define WS_IDX     5283840u    // argmin (int)            32,768
#define WS_CAND    5316608u    // [token][16] int         524,288
#define WS_ICNT    5840896u    // int histogram           8,192   <- memset from here
#define WS_CUR     5849088u    // int cursors             8,192   <- memset through here
#define WS_OFFS    5857280u    // int exclusive offsets   8,192
#define WS_PERM    5865472u    // int token permutation   32,768
#define WS_LPART   5898240u    // per-block loss partials 2,048 doubles (4,096 floats)
#define WS_DW      5914624u    // segment-sum fp32        2,097,152
#define WS_TOTAL   8011776u
#define WS_MEMSET_LEN 16384u   // ICNT + CUR only

// ---- output layout (float offsets) ----
#define O_LOSS 0u
#define O_Q    1u
#define O_IDX  8388609u
#define O_CNT  8421377u
#define O_W    8429569u
#define O_CB   10526721u

typedef __attribute__((ext_vector_type(8))) short bf16x8;
typedef __attribute__((ext_vector_type(4))) float f32x4;

__device__ __forceinline__ void g2lds16(const void* gp, void* lp){
  __builtin_amdgcn_global_load_lds(
      (const __attribute__((address_space(1))) void*)gp,
      (__attribute__((address_space(3))) void*)lp, 16, 0, 0);
}

__device__ __forceinline__ unsigned short f2b(float f){   // fp32 -> bf16 RNE
  unsigned u = __float_as_uint(f);
  return (unsigned short)((u + 0x7FFFu + ((u >> 16) & 1u)) >> 16);
}

__device__ __forceinline__ unsigned umin2(unsigned a, unsigned b){ return a < b ? a : b; }
__device__ __forceinline__ unsigned umax2(unsigned a, unsigned b){ return a > b ? a : b; }

// ============ prep: squared norms, numpy pairwise fp32 order ============
__device__ __forceinline__ float np_pairwise_sq(const float* __restrict__ p, int stride){
  #pragma clang fp contract(off)
  float h[2];
  #pragma unroll
  for (int half = 0; half < 2; half++){
    const float* q = p + half * 128 * stride;
    float r[8];
    #pragma unroll
    for (int j = 0; j < 8; j++){ float z = q[j * stride]; r[j] = z * z; }
    for (int i = 8; i < 128; i += 8){
      #pragma unroll
      for (int j = 0; j < 8; j++){ float z = q[(i + j) * stride]; r[j] = r[j] + z * z; }
    }
    h[half] = ((r[0] + r[1]) + (r[2] + r[3])) + ((r[4] + r[5]) + (r[6] + r[7]));
  }
  return h[0] + h[1];
}

// ============ fused prep: flatb transpose | cb->bf16 | squared norms ============
__global__ void k_prep(const float* __restrict__ x, const float* __restrict__ cb,
                       unsigned short* __restrict__ flatB, unsigned short* __restrict__ cbB,
                       float* __restrict__ a32, float* __restrict__ b32)
{
  __shared__ float tile[64][65];
  const int bx = blockIdx.x;
  const int t = threadIdx.x;
  if (bx < 2048){
    const int b = bx >> 6, ct = (bx >> 4) & 3, ht = bx & 15;
    const int c0 = ct * 64, hw0 = ht * 64;
    const int rr = t >> 4, cc4 = (t & 15) * 4;
    #pragma unroll
    for (int j = 0; j < 4; j++){
      const int crow = rr + j * 16;
      float4 v = *(const float4*)(x + ((size_t)(b * 256 + c0 + crow) << 10) + hw0 + cc4);
      tile[crow][cc4] = v.x; tile[crow][cc4+1] = v.y; tile[crow][cc4+2] = v.z; tile[crow][cc4+3] = v.w;
    }
    __syncthreads();
    #pragma unroll
    for (int j = 0; j < 4; j++){
      const int hwrow = rr + j * 16;
      ushort4 o = { f2b(tile[cc4][hwrow]), f2b(tile[cc4+1][hwrow]),
                    f2b(tile[cc4+2][hwrow]), f2b(tile[cc4+3][hwrow]) };
      *(ushort4*)(flatB + ((size_t)(b * 1024 + hw0 + hwrow) << 8) + c0 + cc4) = o;
    }
  } else if (bx < 4096){
    const int g = (bx - 2048) * 256 + t;    // 524,288
    float4 v = *(const float4*)(cb + (size_t)g * 4);
    ushort4 o = { f2b(v.x), f2b(v.y), f2b(v.z), f2b(v.w) };
    *(ushort4*)(cbB + (size_t)g * 4) = o;
  } else {
    const int g = (bx - 4096) * 256 + t;    // 40,960
    if (g < N_TOK){
      int b = g >> 10, hw = g & 1023;
      a32[g] = np_pairwise_sq(x + (size_t)b * 262144 + hw, 1024);
    } else {
      int k2 = g - N_TOK;
      b32[k2] = np_pairwise_sq(cb + (size_t)k2 * 256, 1);
    }
  }
}

// ============ phase 1: bf16-MFMA distance GEMM + top-8 candidates/half ============
// (best-measured variant: 155.4us, 40% of 16x16-MFMA ceiling)
__launch_bounds__(256, 2)
__global__ void k_dist(const unsigned short* __restrict__ flatB,
                       const unsigned short* __restrict__ cbB,
                       const float* __restrict__ b32,
                       int* __restrict__ cand)
{
  __shared__ __align__(16) unsigned short A1[128 * 128];   // 32 KB: [row][k0..127]
  __shared__ __align__(16) unsigned short Bs[2][128 * 64]; // 2 x 16 KB

  const int tid = threadIdx.x;
  const int bx = blockIdx.x;             // 512 = 256 token-tiles x 2 halves
  const int tt = bx >> 1, h = bx & 1;
  const int tok0 = tt * 128;
  const int wv = tid >> 6, lane = tid & 63;
  const int wy = wv >> 1, wx = wv & 1;
  const int l4 = lane >> 4, lm = lane & 15;

  const unsigned short* fB = flatB + (size_t)tok0 * 256;
  const unsigned short* cB = cbB + (size_t)h * 4096 * 256;

  // ---- stage A1 (k 0..127) and A2 (k 128..255, into Bs region) ----
  {
    const int r = lane >> 4, p = lane & 15;
    #pragma unroll
    for (int j = 0; j < 8; j++){
      const int row = wv * 32 + j * 4 + r;
      const int gc = p ^ (row & 15);
      g2lds16((const char*)fB + (size_t)row * 512 + (gc << 4),
              (char*)A1 + (wv * 32 + j * 4) * 256);
    }
    unsigned short* A2 = &Bs[0][0];
    #pragma unroll
    for (int j = 0; j < 8; j++){
      const int row = wv * 32 + j * 4 + r;
      const int gc = p ^ (row & 15);
      g2lds16((const char*)fB + (size_t)row * 512 + 256 + (gc << 4),
              (char*)A2 + (wv * 32 + j * 4) * 256);
    }
  }
  __syncthreads();

  // ---- A k128..255 fragments -> registers (16 x b128 = 64 VGPR) ----
  bf16x8 a2[4][4];
  {
    const unsigned short* A2 = &Bs[0][0];
    #pragma unroll
    for (int ks4 = 0; ks4 < 4; ks4++)
      #pragma unroll
      for (int ii = 0; ii < 4; ii++){
        const int m = wy * 64 + ii * 16 + lm;
        const int c = ks4 * 4 + l4;
        a2[ks4][ii] = *(const bf16x8*)((const char*)A2 + m * 256 + ((c ^ (m & 15)) << 4));
      }
  }
  __syncthreads();   // A2 regs loaded; Bs region now reusable for B slices

  // ---- loop-invariant address precompute ----
  unsigned aoff[4][4];   // [kg 0..3][ii] byte offsets into A1
  #pragma unroll
  for (int kg = 0; kg < 4; kg++)
    #pragma unroll
    for (int ii = 0; ii < 4; ii++){
      const int m = wy * 64 + ii * 16 + lm;
      const int ca = kg * 4 + l4;
      aoff[kg][ii] = (unsigned)(m * 256 + ((ca ^ (m & 15)) << 4));
    }
  unsigned boff[2][2][4];  // [buf][ks2][jj] byte offsets into Bs
  #pragma unroll
  for (int buf = 0; buf < 2; buf++)
    #pragma unroll
    for (int ks2 = 0; ks2 < 2; ks2++)
      #pragma unroll
      for (int jj = 0; jj < 4; jj++){
        const int n = wx * 64 + jj * 16 + lm;
        const int c2 = ks2 * 4 + l4;
        boff[buf][ks2][jj] = (unsigned)(buf * 16384 + n * 128 + ((c2 ^ (n & 7)) << 4));
      }
  // stageB per-lane invariants
  const char* gBj[4];
  unsigned dstj[4];
  {
    const int r8 = lane >> 3, p = lane & 7;
    #pragma unroll
    for (int j = 0; j < 4; j++){
      const int row = wv * 32 + j * 8 + r8;
      const int gc = p ^ (row & 7);
      gBj[j] = (const char*)cB + (size_t)row * 512 + (gc << 4);
      dstj[j] = (unsigned)((wv * 32 + j * 8) * 128);
    }
  }

  auto stageB = [&](int S2){
    const int ss = S2 & 3, cc = S2 >> 2;
    const int buf = (S2 & 1) * 16384;
    const size_t soff = (size_t)(cc * 65536 + ss * 128);   // scalar (wave-uniform)
    #pragma unroll
    for (int j = 0; j < 4; j++)
      g2lds16(gBj[j] + soff, (char*)Bs + buf + dstj[j]);
  };

  unsigned k1[16], k2[16];
  #pragma unroll
  for (int i = 0; i < 16; i++){ k1[i] = 0xFFFFFFFFu; k2[i] = 0xFFFFFFFFu; }

  f32x4 acc[4][4];
  float bn125[4];

  stageB(0);
  __syncthreads();

  for (int c = 0; c < 32; c++){
    #pragma unroll
    for (int s = 0; s < 4; s++){
      const int S = c * 4 + s;
      if (S + 1 < 128) stageB(S + 1);
      if (s == 0){
        #pragma unroll
        for (int jj = 0; jj < 4; jj++)
          bn125[jj] = b32[h * 4096 + c * 128 + wx * 64 + jj * 16 + lm] + 0.125f;
        #pragma unroll
        for (int ii = 0; ii < 4; ii++)
          #pragma unroll
          for (int jj = 0; jj < 4; jj++)
            acc[ii][jj] = (f32x4){0.f, 0.f, 0.f, 0.f};
      }
      #pragma unroll
      for (int ks2 = 0; ks2 < 2; ks2++){
        const int kg = s * 2 + ks2;          // 0..7 (compile-time)
        bf16x8 bf[4], af[4];
        #pragma unroll
        for (int jj = 0; jj < 4; jj++)
          bf[jj] = *(const bf16x8*)((const char*)Bs + boff[s & 1][ks2][jj]);
        if (kg < 4){
          #pragma unroll
          for (int ii = 0; ii < 4; ii++)
            af[ii] = *(const bf16x8*)((const char*)A1 + aoff[kg][ii]);
        } else {
          #pragma unroll
          for (int ii = 0; ii < 4; ii++) af[ii] = a2[kg - 4][ii];
        }
        #pragma unroll
        for (int ii = 0; ii < 4; ii++)
          #pragma unroll
          for (int jj = 0; jj < 4; jj++)
            acc[ii][jj] = __builtin_amdgcn_mfma_f32_16x16x32_bf16(af[ii], bf[jj], acc[ii][jj], 0, 0, 0);
      }
      if (s == 3){
        // rank by float bits of (b - 2s + 0.125) > 0; (c<<2)|jj packed in low 7 bits
        unsigned pk[4];
        #pragma unroll
        for (int jj = 0; jj < 4; jj++) pk[jj] = (unsigned)((c << 2) | jj);
        #pragma unroll
        for (int ii = 0; ii < 4; ii++){
          #pragma unroll
          for (int r = 0; r < 4; r++){
            const int rk = ii * 4 + r;
            unsigned kb[4];
            #pragma unroll
            for (int jj = 0; jj < 4; jj++){
              const float v = fmaf(-2.f, acc[ii][jj][r], bn125[jj]);
              kb[jj] = (__float_as_uint(v) & 0xFFFFFF80u) | pk[jj];
            }
            // smallest-2-of-4
            const unsigned lo01 = umin2(kb[0], kb[1]), hi01 = umax2(kb[0], kb[1]);
            const unsigned lo23 = umin2(kb[2], kb[3]), hi23 = umax2(kb[2], kb[3]);
            const unsigned s1 = umin2(lo01, lo23);
            const unsigned s2 = umin2(umax2(lo01, lo23), umin2(hi01, hi23));
            // merge two sorted pairs (k1,k2) x (s1,s2) -> top-2
            const unsigned t = umax2(k1[rk], s1);
            k1[rk] = umin2(k1[rk], s1);
            k2[rk] = umin2(umin2(k2[rk], t), s2);
          }
        }
      }
      __syncthreads();
    }
  }

  // ---- finalize keys to (qi<<12)|col and merge: per row, top-8 of 64 keys ----
  const unsigned colbase = (unsigned)(wx * 64 + lm);
  auto fin = [colbase](unsigned key)->unsigned {
    const float v125 = __uint_as_float(key & 0xFFFFFF80u);
    int qi = (int)(v125 * 4194304.f);          // (v + 0.125) * 2^22
    qi = qi < 0 ? 0 : (qi > 0xFFFFF ? 0xFFFFF : qi);
    const unsigned cc = (key >> 2) & 31u, jj = key & 3u;
    return ((unsigned)qi << 12) | (cc * 128u + jj * 16u + colbase);
  };
  unsigned* red = (unsigned*)&A1[0];        // 32 KB = 8192 u32 = [128 rows][64]
  #pragma unroll
  for (int rk = 0; rk < 16; rk++){
    const int srow = wy * 64 + (rk >> 2) * 16 + l4 * 4 + (rk & 3);
    red[srow * 64 + wx * 32 + lm * 2 + 0] = fin(k1[rk]);
    red[srow * 64 + wx * 32 + lm * 2 + 1] = fin(k2[rk]);
  }
  __syncthreads();
  if (tid < 128){
    unsigned best[8];
    #pragma unroll
    for (int j = 0; j < 8; j++) best[j] = 0xFFFFFFFFu;
    for (int i = 0; i < 64; i++){
      unsigned k = red[tid * 64 + i];
      if (k < best[7]){
        best[7] = k;
        #pragma unroll
        for (int j = 7; j > 0; j--){
          if (best[j] < best[j-1]){ unsigned tmp = best[j]; best[j] = best[j-1]; best[j-1] = tmp; }
        }
      }
    }
    const size_t base = ((size_t)(tok0 + tid) * 2 + h) * 8;
    #pragma unroll
    for (int j = 0; j < 8; j++) cand[base + j] = h * 4096 + (int)(best[j] & 0xFFFu);
  }
}

// ========== phase 2: np-fp32-semantics rescore (16 lanes / token) ==========
// 4 tokens per wave; lane = cg*4 + tq (tq = token-in-quad, cg = channel group).
// x reads coalesce over the 4 consecutive tokens (16B segments); cb candidate
// rows load as 4x float4 per lane; reduction = 4-step __shfl_xor butterfly
// (masks 4/8/16/32) shared by all 4 tokens -> ~6x fewer ds_bpermute than the
// 64-lane version. Candidate index is uniform within each 16-lane group.
__global__ void k_pick(const float* __restrict__ x, const float* __restrict__ cb,
                       const float* __restrict__ a32, const float* __restrict__ b32,
                       const int* __restrict__ cand, int* __restrict__ idx,
                       int* __restrict__ icnt, float* __restrict__ out_idx)
{
  const int gt = blockIdx.x * 256 + threadIdx.x;
  const int wid = gt >> 6;                 // 0..8191
  const int lane = gt & 63;
  const int tq = lane & 3, cg = lane >> 2;
  const int n = wid * 4 + tq;              // token
  const int b = n >> 10, hw = n & 1023;

  float z[16];
  {
    const float* xb = x + (((size_t)(b * 256 + cg * 16)) << 10) + hw;
    #pragma unroll
    for (int j = 0; j < 16; j++) z[j] = xb[(size_t)j << 10];
  }
  const float an = a32[n];
  float bestd = 3.4e38f; int besti = 0x7fffffff;
  for (int j = 0; j < 16; j++){
    const int ci = cand[(size_t)n * 16 + j];     // uniform across the 16 lanes
    if (ci < 0 || ci >= KCB) continue;
    const float* ep = cb + (size_t)ci * DIM + cg * 16;
    float4 e0 = *(const float4*)(ep + 0);
    float4 e1 = *(const float4*)(ep + 4);
    float4 e2 = *(const float4*)(ep + 8);
    float4 e3 = *(const float4*)(ep + 12);
    double se = (double)z[0]*e0.x + (double)z[1]*e0.y + (double)z[2]*e0.z + (double)z[3]*e0.w
              + (double)z[4]*e1.x + (double)z[5]*e1.y + (double)z[6]*e1.z + (double)z[7]*e1.w
              + (double)z[8]*e2.x + (double)z[9]*e2.y + (double)z[10]*e2.z + (double)z[11]*e2.w
              + (double)z[12]*e3.x + (double)z[13]*e3.y + (double)z[14]*e3.z + (double)z[15]*e3.w;
    se += __shfl_xor(se, 4, 64);
    se += __shfl_xor(se, 8, 64);
    se += __shfl_xor(se, 16, 64);
    se += __shfl_xor(se, 32, 64);
    const float A = an + b32[ci];
    const float d32 = (float)((double)A - 2.0 * se);
    if (d32 < bestd || (d32 == bestd && ci < besti)){ bestd = d32; besti = ci; }
  }
  if (cg == 0){
    idx[n] = besti;
    atomicAdd(icnt + besti, 1);
    out_idx[n] = (float)besti;
  }
}

// ========== bucket tokens by code (scan fused: each block scans icnt in LDS) ==========
// 128 blocks; every block redundantly computes the exclusive scan of the 8192
// counts (deterministic, identical across blocks). Block 0 also publishes offs
// to global for k_dw.
__global__ void k_perm(const int* __restrict__ idx, const int* __restrict__ icnt,
                       int* __restrict__ cur, int* __restrict__ perm,
                       int* __restrict__ offs)
{
  __shared__ int offs_l[8192];
  __shared__ int sums[256];
  const int tid = threadIdx.x;
  int loc[32];
  int s = 0;
  #pragma unroll
  for (int i = 0; i < 32; i++){ loc[i] = s; s += icnt[tid * 32 + i]; }
  sums[tid] = s;
  #pragma unroll
  for (int off = 1; off < 256; off <<= 1){
    __syncthreads();
    const int add = (tid >= off) ? sums[tid - off] : 0;
    __syncthreads();
    sums[tid] += add;
  }
  __syncthreads();
  const int pre = (tid == 0) ? 0 : sums[tid - 1];
  #pragma unroll
  for (int i = 0; i < 32; i++) offs_l[tid * 32 + i] = pre + loc[i];
  if (blockIdx.x == 0){
    #pragma unroll
    for (int i = 0; i < 32; i++) offs[tid * 32 + i] = pre + loc[i];
  }
  __syncthreads();
  const int t = blockIdx.x * 256 + tid;        // 32,768
  const int code = idx[t];
  const int slot = atomicAdd(cur + code, 1);
  perm[offs_l[code] + slot] = t;
}

// ===================== dw segment-sum: one block per code, no atomics ==========
__global__ void k_dw(const unsigned short* __restrict__ flatB,
                     const int* __restrict__ offs, const int* __restrict__ icnt,
                     const int* __restrict__ perm, float* __restrict__ dw)
{
  const int k = blockIdx.x;                   // 8192
  const int c = threadIdx.x;                  // 256
  const int start = offs[k], cnt = icnt[k];
  float s = 0.f;
  for (int i = 0; i < cnt; i++){
    const int n = perm[start + i];
    s += __uint_as_float(((unsigned)flatB[((size_t)n << 8) + c]) << 16);
  }
  dw[((size_t)k << 8) + c] = s;               // empty code -> exact 0.0
}

// ===================== quantize + loss partials (LDS-tiled cb gather) ==========
__global__ void k_quant(const float* __restrict__ x, const float* __restrict__ cb,
                        const int* __restrict__ idx, float* __restrict__ outq,
                        double* __restrict__ lpart)
{
  __shared__ float qt[64][65];
  __shared__ double wred[4];
  const int bx = blockIdx.x;                  // 2048 = b(32) x ct(4) x ht(16)
  const int tid = threadIdx.x;                // 256
  const int b = bx >> 6, ct = (bx >> 4) & 3, ht = bx & 15;
  const int c0 = ct * 64, hw0 = ht * 64;
  const int n0 = b * 1024 + hw0;

  {
    const int cl = tid & 63, wq = tid >> 6;
    for (int r16 = 0; r16 < 16; r16++){
      const int row = r16 * 4 + wq;
      const int i = idx[n0 + row];            // broadcast
      qt[row][cl] = cb[(size_t)i * DIM + c0 + cl];
    }
  }
  __syncthreads();

  const int cc = tid >> 4;                    // 0..15
  const int hw4 = (tid & 15) * 4;
  double p = 0.0;
  #pragma unroll
  for (int j = 0; j < 4; j++){
    const int cl = cc + j * 16;               // 0..63
    const size_t xo = (((size_t)(b * 256 + c0 + cl)) << 10) + hw0 + hw4;
    float4 xv = *(const float4*)(x + xo);
    float q0 = qt[hw4 + 0][cl];
    float q1 = qt[hw4 + 1][cl];
    float q2 = qt[hw4 + 2][cl];
    float q3 = qt[hw4 + 3][cl];
    float qd0 = q0 - xv.x, qd1 = q1 - xv.y, qd2 = q2 - xv.z, qd3 = q3 - xv.w;
    float4 ov = { xv.x + qd0, xv.y + qd1, xv.z + qd2, xv.w + qd3 };
    *(float4*)(outq + xo) = ov;               // 16B-aligned (hw4 % 4 == 0)
    p += (double)(qd0*qd0 + qd1*qd1 + qd2*qd2 + qd3*qd3);
  }
  #pragma unroll
  for (int o = 32; o > 0; o >>= 1) p += __shfl_down(p, o, 64);
  if ((tid & 63) == 0) wred[tid >> 6] = p;
  __syncthreads();
  if (tid == 0) lpart[bx] = (wred[0] + wred[1]) + (wred[2] + wred[3]);
}

// ============ new_weight + new_codebook + new_count + e_loss (fused) ============
__global__ void k_final(const float* __restrict__ ema_w, const float* __restrict__ dw,
                        const int* __restrict__ icnt, const float* __restrict__ ema_count,
                        const double* __restrict__ lpart, float* __restrict__ out)
{
  const int k = blockIdx.x;                   // 8192
  const int tid = threadIdx.x;                // 256
  float ct1 = ema_count[k] * 0.95f;
  float ct2 = 0.05f * (float)icnt[k];
  float s  = ct1 + ct2;
  float s2 = s + 1e-5f;
  const float DEN = (float)(32768.0 + 8192.0 * 1e-5);
  float nc = (s2 / DEN) * 32768.0f;
  if (tid == 0) out[O_CNT + k] = nc;
  {
    #pragma clang fp contract(off)
    const int t = k * 256 + tid;
    float w = ema_w[t];
    float d = dw[t];
    float t1 = w * 0.95f;
    float t2 = 0.05f * d;
    float nw = t1 + t2;        // np op order; bit-exact for empty codes (d==0)
    out[O_W + t]  = nw;
    out[O_CB + t] = nw / nc;
  }
  if (k == 0){
    __shared__ double sred[256];
    double ls = 0.0;
    for (int i = tid; i < 2048; i += 256) ls += lpart[i];
    sred[tid] = ls;
    __syncthreads();
    for (int off = 128; off > 0; off >>= 1){
      if (tid < off) sred[tid] += sred[tid + off];
      __syncthreads();
    }
    if (tid == 0) out[O_LOSS] = 0.25f * (float)(sred[0] / 8388608.0);
  }
}

// ===================== launch =====================
extern "C" void kernel_launch(void* const* d_in, const int* in_sizes, int n_in,
                              void* d_out, int out_size, void* d_ws, size_t ws_size,
                              hipStream_t stream)
{
  const float* x         = (const float*)d_in[0];
  const float* cb        = (const float*)d_in[1];
  const float* ema_count = (const float*)d_in[2];
  const float* ema_w     = (const float*)d_in[3];
  float* out = (float*)d_out;
  float* ws  = (float*)d_ws;

  unsigned short* flatB = (unsigned short*)(ws + WS_FLATB);
  unsigned short* cbB   = (unsigned short*)(ws + WS_CBB);
  float*  a32    = ws + WS_A32;
  float*  b32    = ws + WS_B32;
  int*    idxp   = (int*)(ws + WS_IDX);
  int*    candp  = (int*)(ws + WS_CAND);
  int*    icnt   = (int*)(ws + WS_ICNT);
  int*    curp   = (int*)(ws + WS_CUR);
  int*    offs   = (int*)(ws + WS_OFFS);
  int*    permp  = (int*)(ws + WS_PERM);
  double* lpart  = (double*)(ws + WS_LPART);
  float*  dwp    = ws + WS_DW;

  (void)hipMemsetAsync(ws + WS_ICNT, 0, (size_t)WS_MEMSET_LEN * sizeof(float), stream);

  k_prep <<<4256, 256, 0, stream>>>(x, cb, flatB, cbB, a32, b32);
  k_dist <<<512,  256, 0, stream>>>(flatB, cbB, b32, candp);
  k_pick <<<2048, 256, 0, stream>>>(x, cb, a32, b32, candp, idxp, icnt, out + O_IDX);
  k_perm <<<128,  256, 0, stream>>>(idxp, icnt, curp, permp, offs);
  k_dw   <<<8192, 256, 0, stream>>>(flatB, offs, icnt, permp, dwp);
  k_quant<<<2048, 256, 0, stream>>>(x, cb, idxp, out + O_Q, lpart);
  k_final<<<8192, 256, 0, stream>>>(ema_w, dwp, icnt, ema_count, lpart, out);
}

// Round 6
// 384.336 us; speedup vs baseline: 1.2038x; 1.0014x over previous
//
#include <hip/hip_runtime.h>
#include <stdint.h>

// Problem constants
#define N_TOK 32768   // B*H*W tokens
#define DIM   256
#define KCB   8192
#define HWSZ  1024

// ---- workspace layout (float offsets) ---- total 8,011,776 floats = 32.0 MB
#define WS_FLATB   0u          // bf16 flat [32768][256]  (4,194,304)
#define WS_CBB     4194304u    // bf16 cb [8192][256]     (1,048,576)
#define WS_A32     5242880u    // np-fp32 ||z||^2         32,768
#define WS_B32     5275648u    // np-fp32 ||e||^2         8,192
#define WS_IDX     5283840u    // argmin (int)            32,768
#define WS_CAND    5316608u    // [token][16] int         524,288
#define WS_ICNT    5840896u    // int histogram           8,192   <- memset from here
#define WS_CUR     5849088u    // int cursors             8,192   <- memset through here
#define WS_OFFS    5857280u    // int exclusive offsets   8,192
#define WS_PERM    5865472u    // int token permutation   32,768
#define WS_LPART   5898240u    // per-block loss partials 2,048 doubles (4,096 floats)
#define WS_DW      5914624u    // (unused now)
#define WS_TOTAL   8011776u
#define WS_MEMSET_LEN 16384u   // ICNT + CUR only

// ---- output layout (float offsets) ----
#define O_LOSS 0u
#define O_Q    1u
#define O_IDX  8388609u
#define O_CNT  8421377u
#define O_W    8429569u
#define O_CB   10526721u

typedef __attribute__((ext_vector_type(8))) short bf16x8;
typedef __attribute__((ext_vector_type(4))) float f32x4;

__device__ __forceinline__ void g2lds16(const void* gp, void* lp){
  __builtin_amdgcn_global_load_lds(
      (const __attribute__((address_space(1))) void*)gp,
      (__attribute__((address_space(3))) void*)lp, 16, 0, 0);
}

__device__ __forceinline__ unsigned short f2b(float f){   // fp32 -> bf16 RNE
  unsigned u = __float_as_uint(f);
  return (unsigned short)((u + 0x7FFFu + ((u >> 16) & 1u)) >> 16);
}

__device__ __forceinline__ unsigned umin2(unsigned a, unsigned b){ return a < b ? a : b; }
__device__ __forceinline__ unsigned umax2(unsigned a, unsigned b){ return a > b ? a : b; }

// ============ prep: squared norms, numpy pairwise fp32 order ============
__device__ __forceinline__ float np_pairwise_sq(const float* __restrict__ p, int stride){
  #pragma clang fp contract(off)
  float h[2];
  #pragma unroll
  for (int half = 0; half < 2; half++){
    const float* q = p + half * 128 * stride;
    float r[8];
    #pragma unroll
    for (int j = 0; j < 8; j++){ float z = q[j * stride]; r[j] = z * z; }
    for (int i = 8; i < 128; i += 8){
      #pragma unroll
      for (int j = 0; j < 8; j++){ float z = q[(i + j) * stride]; r[j] = r[j] + z * z; }
    }
    h[half] = ((r[0] + r[1]) + (r[2] + r[3])) + ((r[4] + r[5]) + (r[6] + r[7]));
  }
  return h[0] + h[1];
}

// ============ fused prep: flatb transpose | cb->bf16 | squared norms ============
__global__ void k_prep(const float* __restrict__ x, const float* __restrict__ cb,
                       unsigned short* __restrict__ flatB, unsigned short* __restrict__ cbB,
                       float* __restrict__ a32, float* __restrict__ b32)
{
  __shared__ float tile[64][65];
  const int bx = blockIdx.x;
  const int t = threadIdx.x;
  if (bx < 2048){
    const int b = bx >> 6, ct = (bx >> 4) & 3, ht = bx & 15;
    const int c0 = ct * 64, hw0 = ht * 64;
    const int rr = t >> 4, cc4 = (t & 15) * 4;
    #pragma unroll
    for (int j = 0; j < 4; j++){
      const int crow = rr + j * 16;
      float4 v = *(const float4*)(x + ((size_t)(b * 256 + c0 + crow) << 10) + hw0 + cc4);
      tile[crow][cc4] = v.x; tile[crow][cc4+1] = v.y; tile[crow][cc4+2] = v.z; tile[crow][cc4+3] = v.w;
    }
    __syncthreads();
    #pragma unroll
    for (int j = 0; j < 4; j++){
      const int hwrow = rr + j * 16;
      ushort4 o = { f2b(tile[cc4][hwrow]), f2b(tile[cc4+1][hwrow]),
                    f2b(tile[cc4+2][hwrow]), f2b(tile[cc4+3][hwrow]) };
      *(ushort4*)(flatB + ((size_t)(b * 1024 + hw0 + hwrow) << 8) + c0 + cc4) = o;
    }
  } else if (bx < 4096){
    const int g = (bx - 2048) * 256 + t;    // 524,288
    float4 v = *(const float4*)(cb + (size_t)g * 4);
    ushort4 o = { f2b(v.x), f2b(v.y), f2b(v.z), f2b(v.w) };
    *(ushort4*)(cbB + (size_t)g * 4) = o;
  } else {
    const int g = (bx - 4096) * 256 + t;    // 40,960
    if (g < N_TOK){
      int b = g >> 10, hw = g & 1023;
      a32[g] = np_pairwise_sq(x + (size_t)b * 262144 + hw, 1024);
    } else {
      int k2 = g - N_TOK;
      b32[k2] = np_pairwise_sq(cb + (size_t)k2 * 256, 1);
    }
  }
}

// ============ phase 1: bf16-MFMA distance GEMM + top-8 candidates/half ============
// (best-measured variant: 155.4us — UNCHANGED)
__launch_bounds__(256, 2)
__global__ void k_dist(const unsigned short* __restrict__ flatB,
                       const unsigned short* __restrict__ cbB,
                       const float* __restrict__ b32,
                       int* __restrict__ cand)
{
  __shared__ __align__(16) unsigned short A1[128 * 128];   // 32 KB: [row][k0..127]
  __shared__ __align__(16) unsigned short Bs[2][128 * 64]; // 2 x 16 KB

  const int tid = threadIdx.x;
  const int bx = blockIdx.x;             // 512 = 256 token-tiles x 2 halves
  const int tt = bx >> 1, h = bx & 1;
  const int tok0 = tt * 128;
  const int wv = tid >> 6, lane = tid & 63;
  const int wy = wv >> 1, wx = wv & 1;
  const int l4 = lane >> 4, lm = lane & 15;

  const unsigned short* fB = flatB + (size_t)tok0 * 256;
  const unsigned short* cB = cbB + (size_t)h * 4096 * 256;

  // ---- stage A1 (k 0..127) and A2 (k 128..255, into Bs region) ----
  {
    const int r = lane >> 4, p = lane & 15;
    #pragma unroll
    for (int j = 0; j < 8; j++){
      const int row = wv * 32 + j * 4 + r;
      const int gc = p ^ (row & 15);
      g2lds16((const char*)fB + (size_t)row * 512 + (gc << 4),
              (char*)A1 + (wv * 32 + j * 4) * 256);
    }
    unsigned short* A2 = &Bs[0][0];
    #pragma unroll
    for (int j = 0; j < 8; j++){
      const int row = wv * 32 + j * 4 + r;
      const int gc = p ^ (row & 15);
      g2lds16((const char*)fB + (size_t)row * 512 + 256 + (gc << 4),
              (char*)A2 + (wv * 32 + j * 4) * 256);
    }
  }
  __syncthreads();

  // ---- A k128..255 fragments -> registers (16 x b128 = 64 VGPR) ----
  bf16x8 a2[4][4];
  {
    const unsigned short* A2 = &Bs[0][0];
    #pragma unroll
    for (int ks4 = 0; ks4 < 4; ks4++)
      #pragma unroll
      for (int ii = 0; ii < 4; ii++){
        const int m = wy * 64 + ii * 16 + lm;
        const int c = ks4 * 4 + l4;
        a2[ks4][ii] = *(const bf16x8*)((const char*)A2 + m * 256 + ((c ^ (m & 15)) << 4));
      }
  }
  __syncthreads();   // A2 regs loaded; Bs region now reusable for B slices

  // ---- loop-invariant address precompute ----
  unsigned aoff[4][4];   // [kg 0..3][ii] byte offsets into A1
  #pragma unroll
  for (int kg = 0; kg < 4; kg++)
    #pragma unroll
    for (int ii = 0; ii < 4; ii++){
      const int m = wy * 64 + ii * 16 + lm;
      const int ca = kg * 4 + l4;
      aoff[kg][ii] = (unsigned)(m * 256 + ((ca ^ (m & 15)) << 4));
    }
  unsigned boff[2][2][4];  // [buf][ks2][jj] byte offsets into Bs
  #pragma unroll
  for (int buf = 0; buf < 2; buf++)
    #pragma unroll
    for (int ks2 = 0; ks2 < 2; ks2++)
      #pragma unroll
      for (int jj = 0; jj < 4; jj++){
        const int n = wx * 64 + jj * 16 + lm;
        const int c2 = ks2 * 4 + l4;
        boff[buf][ks2][jj] = (unsigned)(buf * 16384 + n * 128 + ((c2 ^ (n & 7)) << 4));
      }
  // stageB per-lane invariants
  const char* gBj[4];
  unsigned dstj[4];
  {
    const int r8 = lane >> 3, p = lane & 7;
    #pragma unroll
    for (int j = 0; j < 4; j++){
      const int row = wv * 32 + j * 8 + r8;
      const int gc = p ^ (row & 7);
      gBj[j] = (const char*)cB + (size_t)row * 512 + (gc << 4);
      dstj[j] = (unsigned)((wv * 32 + j * 8) * 128);
    }
  }

  auto stageB = [&](int S2){
    const int ss = S2 & 3, cc = S2 >> 2;
    const int buf = (S2 & 1) * 16384;
    const size_t soff = (size_t)(cc * 65536 + ss * 128);   // scalar (wave-uniform)
    #pragma unroll
    for (int j = 0; j < 4; j++)
      g2lds16(gBj[j] + soff, (char*)Bs + buf + dstj[j]);
  };

  unsigned k1[16], k2[16];
  #pragma unroll
  for (int i = 0; i < 16; i++){ k1[i] = 0xFFFFFFFFu; k2[i] = 0xFFFFFFFFu; }

  f32x4 acc[4][4];
  float bn125[4];

  stageB(0);
  __syncthreads();

  for (int c = 0; c < 32; c++){
    #pragma unroll
    for (int s = 0; s < 4; s++){
      const int S = c * 4 + s;
      if (S + 1 < 128) stageB(S + 1);
      if (s == 0){
        #pragma unroll
        for (int jj = 0; jj < 4; jj++)
          bn125[jj] = b32[h * 4096 + c * 128 + wx * 64 + jj * 16 + lm] + 0.125f;
        #pragma unroll
        for (int ii = 0; ii < 4; ii++)
          #pragma unroll
          for (int jj = 0; jj < 4; jj++)
            acc[ii][jj] = (f32x4){0.f, 0.f, 0.f, 0.f};
      }
      #pragma unroll
      for (int ks2 = 0; ks2 < 2; ks2++){
        const int kg = s * 2 + ks2;          // 0..7 (compile-time)
        bf16x8 bf[4], af[4];
        #pragma unroll
        for (int jj = 0; jj < 4; jj++)
          bf[jj] = *(const bf16x8*)((const char*)Bs + boff[s & 1][ks2][jj]);
        if (kg < 4){
          #pragma unroll
          for (int ii = 0; ii < 4; ii++)
            af[ii] = *(const bf16x8*)((const char*)A1 + aoff[kg][ii]);
        } else {
          #pragma unroll
          for (int ii = 0; ii < 4; ii++) af[ii] = a2[kg - 4][ii];
        }
        #pragma unroll
        for (int ii = 0; ii < 4; ii++)
          #pragma unroll
          for (int jj = 0; jj < 4; jj++)
            acc[ii][jj] = __builtin_amdgcn_mfma_f32_16x16x32_bf16(af[ii], bf[jj], acc[ii][jj], 0, 0, 0);
      }
      if (s == 3){
        // rank by float bits of (b - 2s + 0.125) > 0; (c<<2)|jj packed in low 7 bits
        unsigned pk[4];
        #pragma unroll
        for (int jj = 0; jj < 4; jj++) pk[jj] = (unsigned)((c << 2) | jj);
        #pragma unroll
        for (int ii = 0; ii < 4; ii++){
          #pragma unroll
          for (int r = 0; r < 4; r++){
            const int rk = ii * 4 + r;
            unsigned kb[4];
            #pragma unroll
            for (int jj = 0; jj < 4; jj++){
              const float v = fmaf(-2.f, acc[ii][jj][r], bn125[jj]);
              kb[jj] = (__float_as_uint(v) & 0xFFFFFF80u) | pk[jj];
            }
            // smallest-2-of-4
            const unsigned lo01 = umin2(kb[0], kb[1]), hi01 = umax2(kb[0], kb[1]);
            const unsigned lo23 = umin2(kb[2], kb[3]), hi23 = umax2(kb[2], kb[3]);
            const unsigned s1 = umin2(lo01, lo23);
            const unsigned s2 = umin2(umax2(lo01, lo23), umin2(hi01, hi23));
            // merge two sorted pairs (k1,k2) x (s1,s2) -> top-2
            const unsigned t = umax2(k1[rk], s1);
            k1[rk] = umin2(k1[rk], s1);
            k2[rk] = umin2(umin2(k2[rk], t), s2);
          }
        }
      }
      __syncthreads();
    }
  }

  // ---- finalize keys to (qi<<12)|col and merge: per row, top-8 of 64 keys ----
  const unsigned colbase = (unsigned)(wx * 64 + lm);
  auto fin = [colbase](unsigned key)->unsigned {
    const float v125 = __uint_as_float(key & 0xFFFFFF80u);
    int qi = (int)(v125 * 4194304.f);          // (v + 0.125) * 2^22
    qi = qi < 0 ? 0 : (qi > 0xFFFFF ? 0xFFFFF : qi);
    const unsigned cc = (key >> 2) & 31u, jj = key & 3u;
    return ((unsigned)qi << 12) | (cc * 128u + jj * 16u + colbase);
  };
  unsigned* red = (unsigned*)&A1[0];        // 32 KB = 8192 u32 = [128 rows][64]
  #pragma unroll
  for (int rk = 0; rk < 16; rk++){
    const int srow = wy * 64 + (rk >> 2) * 16 + l4 * 4 + (rk & 3);
    red[srow * 64 + wx * 32 + lm * 2 + 0] = fin(k1[rk]);
    red[srow * 64 + wx * 32 + lm * 2 + 1] = fin(k2[rk]);
  }
  __syncthreads();
  if (tid < 128){
    unsigned best[8];
    #pragma unroll
    for (int j = 0; j < 8; j++) best[j] = 0xFFFFFFFFu;
    for (int i = 0; i < 64; i++){
      unsigned k = red[tid * 64 + i];
      if (k < best[7]){
        best[7] = k;
        #pragma unroll
        for (int j = 7; j > 0; j--){
          if (best[j] < best[j-1]){ unsigned tmp = best[j]; best[j] = best[j-1]; best[j-1] = tmp; }
        }
      }
    }
    const size_t base = ((size_t)(tok0 + tid) * 2 + h) * 8;
    #pragma unroll
    for (int j = 0; j < 8; j++) cand[base + j] = h * 4096 + (int)(best[j] & 0xFFFu);
  }
}

// ========== phase 2: rescore + FUSED quantize/loss (16 lanes / token) ==========
// 4 tokens per wave; lane = cg*4 + tq. After the rescore butterfly, all 16
// lanes of a token group hold the same besti. The wave already has the full
// 256-channel x slice in registers (z[16] x 16 lanes), so quantize is: reload
// cb[besti] slice (L2-hot, 64B/lane), qd = q - z, store ov = z + qd (the exact
// fp32 exprs of the old k_quant), and reduce sum(qd^2) into lpart[2048].
__global__ void k_pick(const float* __restrict__ x, const float* __restrict__ cb,
                       const float* __restrict__ a32, const float* __restrict__ b32,
                       const int* __restrict__ cand, int* __restrict__ idx,
                       int* __restrict__ icnt, float* __restrict__ out_idx,
                       float* __restrict__ outq, double* __restrict__ lpart)
{
  __shared__ double wred[4];
  const int gt = blockIdx.x * 256 + threadIdx.x;
  const int wid = gt >> 6;                 // 0..8191
  const int lane = gt & 63;
  const int tq = lane & 3, cg = lane >> 2;
  const int n = wid * 4 + tq;              // token
  const int b = n >> 10, hw = n & 1023;

  const size_t xbase = (((size_t)(b * 256 + cg * 16)) << 10) + hw;
  float z[16];
  #pragma unroll
  for (int j = 0; j < 16; j++) z[j] = x[xbase + ((size_t)j << 10)];

  const float an = a32[n];
  float bestd = 3.4e38f; int besti = 0x7fffffff;
  for (int j = 0; j < 16; j++){
    const int ci = cand[(size_t)n * 16 + j];     // uniform across the 16 lanes
    if (ci < 0 || ci >= KCB) continue;
    const float* ep = cb + (size_t)ci * DIM + cg * 16;
    float4 e0 = *(const float4*)(ep + 0);
    float4 e1 = *(const float4*)(ep + 4);
    float4 e2 = *(const float4*)(ep + 8);
    float4 e3 = *(const float4*)(ep + 12);
    double se = (double)z[0]*e0.x + (double)z[1]*e0.y + (double)z[2]*e0.z + (double)z[3]*e0.w
              + (double)z[4]*e1.x + (double)z[5]*e1.y + (double)z[6]*e1.z + (double)z[7]*e1.w
              + (double)z[8]*e2.x + (double)z[9]*e2.y + (double)z[10]*e2.z + (double)z[11]*e2.w
              + (double)z[12]*e3.x + (double)z[13]*e3.y + (double)z[14]*e3.z + (double)z[15]*e3.w;
    se += __shfl_xor(se, 4, 64);
    se += __shfl_xor(se, 8, 64);
    se += __shfl_xor(se, 16, 64);
    se += __shfl_xor(se, 32, 64);
    const float A = an + b32[ci];
    const float d32 = (float)((double)A - 2.0 * se);
    if (d32 < bestd || (d32 == bestd && ci < besti)){ bestd = d32; besti = ci; }
  }

  // ---- fused quantize + loss ----
  double p = 0.0;
  {
    const float* ep = cb + (size_t)besti * DIM + cg * 16;
    float4 e0 = *(const float4*)(ep + 0);
    float4 e1 = *(const float4*)(ep + 4);
    float4 e2 = *(const float4*)(ep + 8);
    float4 e3 = *(const float4*)(ep + 12);
    float q[16] = { e0.x, e0.y, e0.z, e0.w, e1.x, e1.y, e1.z, e1.w,
                    e2.x, e2.y, e2.z, e2.w, e3.x, e3.y, e3.z, e3.w };
    #pragma unroll
    for (int j = 0; j < 16; j++){
      const float qd = q[j] - z[j];
      outq[xbase + ((size_t)j << 10)] = z[j] + qd;
      p += (double)(qd * qd);
    }
  }
  #pragma unroll
  for (int o = 32; o > 0; o >>= 1) p += __shfl_down(p, o, 64);
  if ((threadIdx.x & 63) == 0) wred[threadIdx.x >> 6] = p;

  if (cg == 0){
    idx[n] = besti;
    atomicAdd(icnt + besti, 1);
    out_idx[n] = (float)besti;
  }
  __syncthreads();
  if (threadIdx.x == 0) lpart[blockIdx.x] = (wred[0] + wred[1]) + (wred[2] + wred[3]);
}

// ========== bucket tokens by code (scan fused: each block scans icnt in LDS) ==========
__global__ void k_perm(const int* __restrict__ idx, const int* __restrict__ icnt,
                       int* __restrict__ cur, int* __restrict__ perm,
                       int* __restrict__ offs)
{
  __shared__ int offs_l[8192];
  __shared__ int sums[256];
  const int tid = threadIdx.x;
  int loc[32];
  int s = 0;
  #pragma unroll
  for (int i = 0; i < 32; i++){ loc[i] = s; s += icnt[tid * 32 + i]; }
  sums[tid] = s;
  #pragma unroll
  for (int off = 1; off < 256; off <<= 1){
    __syncthreads();
    const int add = (tid >= off) ? sums[tid - off] : 0;
    __syncthreads();
    sums[tid] += add;
  }
  __syncthreads();
  const int pre = (tid == 0) ? 0 : sums[tid - 1];
  #pragma unroll
  for (int i = 0; i < 32; i++) offs_l[tid * 32 + i] = pre + loc[i];
  if (blockIdx.x == 0){
    #pragma unroll
    for (int i = 0; i < 32; i++) offs[tid * 32 + i] = pre + loc[i];
  }
  __syncthreads();
  const int t = blockIdx.x * 256 + tid;        // 32,768
  const int code = idx[t];
  const int slot = atomicAdd(cur + code, 1);
  perm[offs_l[code] + slot] = t;
}

// ====== dw segment-sum + new_weight/new_codebook/new_count + e_loss (fused) ======
// block k: accumulate dw[k][c] in a register (same float summation order as the
// old k_dw: empty code -> exact 0.0), then apply the EMA update and codebook
// divide directly (identical fp32 expression order as the old k_final).
// Block 0 additionally reduces the 2048 loss partials.
__global__ void k_dwf(const unsigned short* __restrict__ flatB,
                      const int* __restrict__ offs, const int* __restrict__ icnt,
                      const int* __restrict__ perm,
                      const float* __restrict__ ema_w, const float* __restrict__ ema_count,
                      const double* __restrict__ lpart, float* __restrict__ out)
{
  const int k = blockIdx.x;                   // 8192
  const int c = threadIdx.x;                  // 256
  const int start = offs[k], cnt = icnt[k];
  float s = 0.f;
  for (int i = 0; i < cnt; i++){
    const int n = perm[start + i];
    s += __uint_as_float(((unsigned)flatB[((size_t)n << 8) + c]) << 16);
  }
  // new_count (same exprs as before)
  float ct1 = ema_count[k] * 0.95f;
  float ct2 = 0.05f * (float)cnt;
  float sc  = ct1 + ct2;
  float sc2 = sc + 1e-5f;
  const float DEN = (float)(32768.0 + 8192.0 * 1e-5);
  float nc = (sc2 / DEN) * 32768.0f;
  if (c == 0) out[O_CNT + k] = nc;
  {
    #pragma clang fp contract(off)
    const int t = k * 256 + c;
    float w = ema_w[t];
    float t1 = w * 0.95f;
    float t2 = 0.05f * s;
    float nw = t1 + t2;        // np op order; bit-exact for empty codes (s==0)
    out[O_W + t]  = nw;
    out[O_CB + t] = nw / nc;
  }
  if (k == 0){
    __shared__ double sred[256];
    double ls = 0.0;
    for (int i = c; i < 2048; i += 256) ls += lpart[i];
    sred[c] = ls;
    __syncthreads();
    for (int off = 128; off > 0; off >>= 1){
      if (c < off) sred[c] += sred[c + off];
      __syncthreads();
    }
    if (c == 0) out[O_LOSS] = 0.25f * (float)(sred[0] / 8388608.0);
  }
}

// ===================== launch =====================
extern "C" void kernel_launch(void* const* d_in, const int* in_sizes, int n_in,
                              void* d_out, int out_size, void* d_ws, size_t ws_size,
                              hipStream_t stream)
{
  const float* x         = (const float*)d_in[0];
  const float* cb        = (const float*)d_in[1];
  const float* ema_count = (const float*)d_in[2];
  const float* ema_w     = (const float*)d_in[3];
  float* out = (float*)d_out;
  float* ws  = (float*)d_ws;

  unsigned short* flatB = (unsigned short*)(ws + WS_FLATB);
  unsigned short* cbB   = (unsigned short*)(ws + WS_CBB);
  float*  a32    = ws + WS_A32;
  float*  b32    = ws + WS_B32;
  int*    idxp   = (int*)(ws + WS_IDX);
  int*    candp  = (int*)(ws + WS_CAND);
  int*    icnt   = (int*)(ws + WS_ICNT);
  int*    curp   = (int*)(ws + WS_CUR);
  int*    offs   = (int*)(ws + WS_OFFS);
  int*    permp  = (int*)(ws + WS_PERM);
  double* lpart  = (double*)(ws + WS_LPART);

  (void)hipMemsetAsync(ws + WS_ICNT, 0, (size_t)WS_MEMSET_LEN * sizeof(float), stream);

  k_prep <<<4256, 256, 0, stream>>>(x, cb, flatB, cbB, a32, b32);
  k_dist <<<512,  256, 0, stream>>>(flatB, cbB, b32, candp);
  k_pick <<<2048, 256, 0, stream>>>(x, cb, a32, b32, candp, idxp, icnt,
                                    out + O_IDX, out + O_Q, lpart);
  k_perm <<<128,  256, 0, stream>>>(idxp, icnt, curp, permp, offs);
  k_dwf  <<<8192, 256, 0, stream>>>(flatB, offs, icnt, permp, ema_w, ema_count,
                                    lpart, out);
}